// Round 6
// baseline (386.007 us; speedup 1.0000x reference)
//
#include <hip/hip_runtime.h>
#include <cmath>

typedef unsigned short ush;  // bf16 raw bits
typedef __attribute__((ext_vector_type(8))) short short8;
typedef __attribute__((ext_vector_type(4))) float floatx4;

static constexpr int N_P = 100000, N_D = 1000, N_S = 5000, NT = N_P + N_D + N_S;
static constexpr int NC = 111000;  // concatenated dst slots: r0:1000 | r1:100000 | r2:5000 | r3:5000
static constexpr int E_TOT = 800000;

// hist-CSR geometry
static constexpr int NB0 = 128, NB2 = 64, NB3 = 64;
static constexpr int CH0 = (300000 + NB0 - 1) / NB0;  // 2344
static constexpr int CH2 = (100000 + NB2 - 1) / NB2;  // 1563
static constexpr int HB0_OFF = 0;
static constexpr int HB2_OFF = NB0 * 1000;            // 128000
static constexpr int HB3_OFF = HB2_OFF + NB2 * 5000;  // 448000 -> total 768000
static constexpr int NCH0 = NB0 / 16, NCH2 = NB2 / 16;  // 8, 4
static constexpr int CS0_OFF = 0;
static constexpr int CS2_OFF = NCH0 * 1000;            // 8000
static constexpr int CS3_OFF = CS2_OFF + NCH2 * 5000;  // 28000 -> total 48000
static constexpr int NHIST = NB0 + NB2 + NB3;          // 256
static constexpr int NBLK_R1 = (300000 + 255) / 256;   // 1172
static constexpr int NZB = (100000 + 255) / 256;       // 391

__device__ __forceinline__ float b2f(ush b) { return __uint_as_float(((unsigned)b) << 16); }
__device__ __forceinline__ ush f2b(float f) {
    unsigned u = __float_as_uint(f);
    return (ush)((u + 0x7FFFu + ((u >> 16) & 1u)) >> 16);
}

// canonical weight-block offsets (bf16 elements), d_in[3..20]
static constexpr size_t OFF_WINP = 0;
static constexpr size_t OFF_BINP = 4096;
static constexpr size_t OFF_WIND = 4160;
static constexpr size_t OFF_BIND = 12352;
static constexpr size_t OFF_WINS = 12416;
static constexpr size_t OFF_BINS = 16512;
static constexpr size_t OFF_WK = 16576;
static constexpr size_t OFF_BK = 41152;
static constexpr size_t OFF_WQ = 41536;
static constexpr size_t OFF_BQ = 66112;
static constexpr size_t OFF_WV = 66496;
static constexpr size_t OFF_BV = 91072;
static constexpr size_t OFF_WA = 91456;
static constexpr size_t OFF_BA = 116032;
static constexpr size_t OFF_AREL = 116416;
static constexpr size_t OFF_MREL = 124608;
static constexpr size_t OFF_PREL = 132800;
static constexpr size_t OFF_SKIP = 132832;
static constexpr size_t CW_TOTAL = 132838;
static constexpr int NCONVB = (int)((CW_TOTAL + 255) / 256);  // 519
static constexpr int NSCB = (NC + 1 + 255) / 256;             // 434

// fragment-layout weight buffer (ush elements)
static constexpr size_t TWINP = 0;      // 4096  (64x64)
static constexpr size_t TWIND = 4096;   // 8192  (128x64)
static constexpr size_t TWINS = 12288;  // 4096
static constexpr size_t TWQO = 16384;   // 6*4096 (l*3+t)
static constexpr size_t TWAO = 40960;   // 6*4096
static constexpr size_t TW_TOTAL = 65536;
static constexpr int NTWB = (int)(TW_TOTAL / 256);  // 256

struct ConvArgs {
    const void* src[18];
    long cum[19];
    int fl[18];  // 1 = fp32 source, 0 = bf16 source (host-derived from in_sizes)
};

struct CsrB {
    const int* ei[3];  // r0, r2, r3 edge arrays
    const int* ei1;    // r1
};

__device__ __forceinline__ void hist_geom(int b, const CsrB& c, int& r, const int*& ei, int& E,
                                          int& ndst, int& e0, int& e1, int& hb) {
    if (b < NB0) {
        r = 0; ei = c.ei[0]; E = 300000; ndst = 1000;
        e0 = b * CH0; hb = HB0_OFF + b * 1000;
    } else if (b < NB0 + NB2) {
        r = 1; ei = c.ei[1]; E = 100000; ndst = 5000;
        e0 = (b - NB0) * CH2; hb = HB2_OFF + (b - NB0) * 5000;
    } else {
        r = 2; ei = c.ei[2]; E = 100000; ndst = 5000;
        e0 = (b - NB0 - NB2) * CH2; hb = HB3_OFF + (b - NB0 - NB2) * 5000;
    }
    e1 = min(E, e0 + ((r == 0) ? CH0 : CH2));
}

__device__ __forceinline__ bool cs_geom(int g, int& idx0, int& step) {
    if (g >= 48000) return false;
    if (g < 8000) {
        int c = g / 1000, d = g % 1000;
        idx0 = HB0_OFF + c * 16 * 1000 + d; step = 1000;
    } else if (g < 28000) {
        int gg = g - 8000, c = gg / 5000, d = gg % 5000;
        idx0 = HB2_OFF + c * 16 * 5000 + d; step = 5000;
    } else {
        int gg = g - 28000, c = gg / 5000, d = gg % 5000;
        idx0 = HB3_OFF + c * 16 * 5000 + d; step = 5000;
    }
    return true;
}

// ---------------------------------------------------------------------------
// K1: convert weights | zero CNT r1 | histograms | fragment-transpose weights.
// Fragment layout for [K][64] weight: frag f = s*4+c holds, for lane l elem j:
//   W[(32s + ((l>>4)<<3) + j)*64 + 16c + (l&15)]   at  TW[f*512 + l*8 + j].
// ---------------------------------------------------------------------------
__global__ __launch_bounds__(256) void k1_kernel(ConvArgs a, ush* __restrict__ dst,
                                                 ush* __restrict__ tw,
                                                 int* __restrict__ cnt_r1, CsrB c,
                                                 int* __restrict__ HB) {
    const int b = blockIdx.x;
    if (b < NCONVB) {
        long g = (long)b * 256 + threadIdx.x;
        if (g >= (long)CW_TOTAL) return;
        int t = 0;
        while (g >= a.cum[t + 1]) t++;
        long i = g - a.cum[t];
        float v = a.fl[t] ? ((const float*)a.src[t])[i] : b2f(((const ush*)a.src[t])[i]);
        dst[g] = f2b(v);
    } else if (b < NCONVB + NZB) {
        int g = (b - NCONVB) * 256 + threadIdx.x;
        if (g < 100000) cnt_r1[g] = 0;
    } else if (b < NCONVB + NZB + NHIST) {
        __shared__ int h[5000];
        int r, E, ndst, e0, e1, hb;
        const int* ei;
        hist_geom(b - NCONVB - NZB, c, r, ei, E, ndst, e0, e1, hb);
        for (int d = threadIdx.x; d < ndst; d += 256) h[d] = 0;
        __syncthreads();
        for (int e = e0 + threadIdx.x; e < e1; e += 256) atomicAdd(&h[ei[E + e]], 1);
        __syncthreads();
        for (int d = threadIdx.x; d < ndst; d += 256) HB[hb + d] = h[d];
    } else {
        int g = (b - NCONVB - NZB - NHIST) * 256 + threadIdx.x;  // [0, 65536)
        const void* src; int fl; long ibase; int e;
        if (g < 4096) { src = a.src[0]; fl = a.fl[0]; e = g; ibase = 0; }
        else if (g < 12288) { src = a.src[2]; fl = a.fl[2]; e = g - 4096; ibase = 0; }
        else if (g < 16384) { src = a.src[4]; fl = a.fl[4]; e = g - 12288; ibase = 0; }
        else if (g < 40960) { int ee = g - 16384; src = a.src[8]; fl = a.fl[8];
                              e = ee & 4095; ibase = (long)(ee >> 12) * 4096; }
        else { int ee = g - 40960; src = a.src[12]; fl = a.fl[12];
               e = ee & 4095; ibase = (long)(ee >> 12) * 4096; }
        int f = e >> 9, l = (e >> 3) & 63, j = e & 7;
        int s = f >> 2, cc = f & 3;
        long in = ibase + (long)(32 * s + ((l >> 4) << 3) + j) * 64 + 16 * cc + (l & 15);
        float v = fl ? ((const float*)src)[in] : b2f(((const ush*)src)[in]);
        tw[g] = f2b(v);
    }
}

// ---------------------------------------------------------------------------
// MFMA building blocks: memcpy B-staging from fragment-layout weights,
// LDS-staged coalesced output stores.
// ---------------------------------------------------------------------------
template <int K>
__device__ __forceinline__ void stage_A(short* sA, const ush* __restrict__ X, int M, int row0) {
    for (int cid = threadIdx.x; cid < 64 * K / 8; cid += 256) {
        int r = cid / (K / 8), c0 = (cid % (K / 8)) * 8;
        int row = row0 + r;
        short8 v = {0, 0, 0, 0, 0, 0, 0, 0};
        if (row < M) v = *(const short8*)(const void*)(X + (size_t)row * K + c0);
        *(short8*)(&sA[r * (K + 8) + c0]) = v;
    }
}

template <int K>
__device__ __forceinline__ void stage_A_raw(short* sA, const void* __restrict__ X, int f,
                                            int M, int row0) {
    for (int cid = threadIdx.x; cid < 64 * K / 8; cid += 256) {
        int r = cid / (K / 8), c0 = (cid % (K / 8)) * 8;
        int row = row0 + r;
        short8 v = {0, 0, 0, 0, 0, 0, 0, 0};
        if (row < M) {
            if (f) {
                const floatx4* fp = (const floatx4*)((const float*)X + (size_t)row * K + c0);
                floatx4 f0 = fp[0], f1 = fp[1];
#pragma unroll
                for (int j = 0; j < 4; j++) v[j] = (short)f2b(f0[j]);
#pragma unroll
                for (int j = 0; j < 4; j++) v[4 + j] = (short)f2b(f1[j]);
            } else {
                v = *(const short8*)(const void*)((const ush*)X + (size_t)row * K + c0);
            }
        }
        *(short8*)(&sA[r * (K + 8) + c0]) = v;
    }
}

// W is fragment-layout. Output 64x64, staged through sB region (free after MFMA).
template <int K>
__device__ __forceinline__ void gemm_core64(const short* sA, short* sB,
                                            const ush* __restrict__ W, const ush* __restrict__ Bb,
                                            ush* __restrict__ Y, int M, int row0) {
    constexpr int NF = (K / 32) * 4;
    const int tid = threadIdx.x;
    for (int u = tid; u < NF * 64; u += 256)
        *(short8*)(&sB[u * 8]) = *(const short8*)(const void*)(W + (size_t)u * 8);
    __syncthreads();
    const int w = tid >> 6, l = tid & 63;
    floatx4 acc[4];
#pragma unroll
    for (int c = 0; c < 4; c++) {
        float bv = b2f(Bb[16 * c + (l & 15)]);
        acc[c] = (floatx4){bv, bv, bv, bv};
    }
#pragma unroll
    for (int s = 0; s < K / 32; s++) {
        short8 a = *(const short8*)(&sA[(16 * w + (l & 15)) * (K + 8) + 32 * s + ((l >> 4) << 3)]);
#pragma unroll
        for (int c = 0; c < 4; c++) {
            short8 b = *(const short8*)(&sB[(s * 4 + c) * 512 + l * 8]);
            acc[c] = __builtin_amdgcn_mfma_f32_16x16x32_bf16(a, b, acc[c], 0, 0, 0);
        }
    }
    __syncthreads();
#pragma unroll
    for (int c = 0; c < 4; c++)
#pragma unroll
        for (int r = 0; r < 4; r++)
            sB[(16 * w + ((l >> 4) << 2) + r) * 72 + 16 * c + (l & 15)] =
                (short)f2b(acc[c][r]);
    __syncthreads();
    for (int u = tid; u < 512; u += 256) {
        int r = u >> 3, c0 = (u & 7) * 8;
        int row = row0 + r;
        if (row < M)
            *(short8*)(Y + (size_t)row * 64 + c0) = *(const short8*)(&sB[r * 72 + c0]);
    }
}

// Wide QKV gemm: K=64, NG groups of 16 output cols. c<4 -> Q; [4,12) -> relA KV;
// [12,20) -> relB KV. Five ld-64 output panels (KV split into K-half/V-half arrays),
// each staged through LDS for coalesced short8 stores.
template <int NG>
__device__ __forceinline__ void gemm_wide(const short* sA, short* sB,
                                          const ush* __restrict__ Wq, const ush* __restrict__ Bq,
                                          ush* __restrict__ Yq,
                                          const ush* __restrict__ WeA,
                                          ush* __restrict__ YAk, ush* __restrict__ YAv,
                                          const ush* __restrict__ WeB,
                                          ush* __restrict__ YBk, ush* __restrict__ YBv,
                                          int M, int row0) {
    constexpr int NF = 2 * NG;
    const int tid = threadIdx.x;
    for (int u = tid; u < NF * 64; u += 256) {
        int f = u >> 6, k = u & 63;
        int s = f / NG, c = f % NG;
        const ush* src;
        if (c < 4) src = Wq + (size_t)(s * 4 + c) * 512;
        else if (c < 12) src = WeA + (size_t)(s * 8 + (c - 4)) * 512;
        else src = WeB + (size_t)(s * 8 + (c - 12)) * 512;
        *(short8*)(&sB[f * 512 + k * 8]) = *(const short8*)(const void*)(src + k * 8);
    }
    __syncthreads();
    const int w = tid >> 6, l = tid & 63;
    floatx4 acc[NG];
#pragma unroll
    for (int c = 0; c < NG; c++) {
        float bv;
        if (c < 4) bv = b2f(Bq[16 * c + (l & 15)]);
        else if (c < 12) bv = b2f(WeA[8192 + 16 * (c - 4) + (l & 15)]);
        else bv = b2f(WeB[8192 + 16 * (c - 12) + (l & 15)]);
        acc[c] = (floatx4){bv, bv, bv, bv};
    }
#pragma unroll
    for (int s = 0; s < 2; s++) {
        short8 a = *(const short8*)(&sA[(16 * w + (l & 15)) * 72 + 32 * s + ((l >> 4) << 3)]);
#pragma unroll
        for (int c = 0; c < NG; c++) {
            short8 b = *(const short8*)(&sB[(s * NG + c) * 512 + l * 8]);
            acc[c] = __builtin_amdgcn_mfma_f32_16x16x32_bf16(a, b, acc[c], 0, 0, 0);
        }
    }
    ush* dst[5] = {Yq, YAk, YAv, YBk, YBv};
#pragma unroll
    for (int cg = 0; cg < NG / 4; cg++) {
        __syncthreads();
#pragma unroll
        for (int c2 = 0; c2 < 4; c2++)
#pragma unroll
            for (int r = 0; r < 4; r++)
                sB[(16 * w + ((l >> 4) << 2) + r) * 72 + 16 * c2 + (l & 15)] =
                    (short)f2b(acc[cg * 4 + c2][r]);
        __syncthreads();
        ush* Y = dst[cg];
        for (int u = tid; u < 512; u += 256) {
            int r = u >> 3, c0 = (u & 7) * 8;
            int row = row0 + r;
            if (row < M)
                *(short8*)(Y + (size_t)row * 64 + c0) = *(const short8*)(&sB[r * 72 + c0]);
        }
    }
}

// ---------------------------------------------------------------------------
// K2: fused input projections | chunk-scan | r1 counts. Dyn LDS: 33792 B.
// ---------------------------------------------------------------------------
struct K2Args {
    const void* raw[3];
    int f[3];
    const ush* W[3];   // fragment layout (TW)
    const ush* Bb[3];
    ush* X;
    const int* HB;
    int* CS;
    int* cnt;
    const int* ei1;
};

__global__ __launch_bounds__(256) void k2_kernel(K2Args a) {
    extern __shared__ short smem[];
    const int b = blockIdx.x;
    if (b < 1658) {
        if (b < 1563) {
            short* sA = smem; short* sB = smem + 64 * 72;
            stage_A_raw<64>(sA, a.raw[0], a.f[0], N_P, b * 64);
            gemm_core64<64>(sA, sB, a.W[0], a.Bb[0], a.X, N_P, b * 64);
        } else if (b < 1579) {
            short* sA = smem; short* sB = smem + 64 * 136;
            stage_A_raw<128>(sA, a.raw[1], a.f[1], N_D, (b - 1563) * 64);
            gemm_core64<128>(sA, sB, a.W[1], a.Bb[1], a.X + (size_t)N_P * 64, N_D,
                             (b - 1563) * 64);
        } else {
            short* sA = smem; short* sB = smem + 64 * 72;
            stage_A_raw<64>(sA, a.raw[2], a.f[2], N_S, (b - 1579) * 64);
            gemm_core64<64>(sA, sB, a.W[2], a.Bb[2], a.X + (size_t)(N_P + N_D) * 64, N_S,
                            (b - 1579) * 64);
        }
    } else if (b < 1701) {
        int d = (b - 1658) * 256 + threadIdx.x;
        if (d >= 11000) return;
        int ld_, nch, base, step, cs0, csstep, roff;
        if (d < 1000) { ld_ = d; nch = NCH0; base = HB0_OFF + ld_; step = 1000;
                        cs0 = CS0_OFF + ld_; csstep = 1000; roff = 0; }
        else if (d < 6000) { ld_ = d - 1000; nch = NCH2; base = HB2_OFF + ld_; step = 5000;
                             cs0 = CS2_OFF + ld_; csstep = 5000; roff = 101000; }
        else { ld_ = d - 6000; nch = NCH2; base = HB3_OFF + ld_; step = 5000;
               cs0 = CS3_OFF + ld_; csstep = 5000; roff = 106000; }
        int run = 0;
        for (int cc = 0; cc < nch; cc++) {
            int s = 0;
#pragma unroll
            for (int bb = 0; bb < 16; bb++) s += a.HB[base + (cc * 16 + bb) * step];
            a.CS[cs0 + cc * csstep] = run;
            run += s;
        }
        a.cnt[roff + ld_] = run;
    } else {
        int g = (b - 1701) * 256 + threadIdx.x;
        if (g < 300000) atomicAdd(&a.cnt[1000 + a.ei1[300000 + g]], 1);
    }
}

// ---------------------------------------------------------------------------
// K3: scanA | eff weight folding, emitted directly in fragment layout.
// ---------------------------------------------------------------------------
__global__ __launch_bounds__(256) void k3_kernel(const int* __restrict__ cnt,
                                                 int* __restrict__ tmp,
                                                 int* __restrict__ part,
                                                 const ush* __restrict__ CW,
                                                 ush* __restrict__ weff) {
    const int b = blockIdx.x;
    if (b < 109) {
        __shared__ int ls[256];
        const int t = threadIdx.x;
        const int base = b * 1024 + t * 4;
        int v[4];
#pragma unroll
        for (int j = 0; j < 4; j++) v[j] = (base + j < NC) ? cnt[base + j] : 0;
        int tsum = v[0] + v[1] + v[2] + v[3];
        ls[t] = tsum;
        __syncthreads();
        for (int off = 1; off < 256; off <<= 1) {
            int y = (t >= off) ? ls[t - off] : 0;
            __syncthreads();
            ls[t] += y;
            __syncthreads();
        }
        int run = ls[t] - tsum;
#pragma unroll
        for (int j = 0; j < 4; j++) {
            if (base + j < NC) tmp[base + j] = run;
            run += v[j];
        }
        if (t == 255) part[b] = ls[255];
    } else {
        const int eb = b - 109;  // l*4+r
        const int l = eb >> 2, r = eb & 3;
        const int st_of[4] = {0, 1, 1, 0};
        const int st = st_of[r];
        ush* out = weff + (size_t)eb * 8320;
        for (int idx = threadIdx.x; idx < 8320; idx += 256) {
            int k, n;
            if (idx < 8192) {
                int f = idx >> 9, ll = (idx >> 3) & 63, j = idx & 7;
                int s = f >> 3, c = f & 7;
                k = 32 * s + ((ll >> 4) << 3) + j;
                n = 16 * c + (ll & 15);
            } else { k = -1; n = idx - 8192; }
            int kv = n >= 64;
            int jj = n & 63, h = jj >> 4, e = jj & 15;
            const ush* W = CW + (kv ? OFF_WV : OFF_WK) + (size_t)(l * 3 + st) * 4096;
            const ush* B = CW + (kv ? OFF_BV : OFF_BK) + (size_t)(l * 3 + st) * 64;
            const ush* R = CW + (kv ? OFF_MREL : OFF_AREL) + (size_t)(l * 4 + r) * 1024;
            float acc = 0.f;
            if (k >= 0) {
#pragma unroll
                for (int d = 0; d < 16; d++)
                    acc += b2f(W[k * 64 + h * 16 + d]) * b2f(R[h * 256 + d * 16 + e]);
            } else {
#pragma unroll
                for (int d = 0; d < 16; d++)
                    acc += b2f(B[h * 16 + d]) * b2f(R[h * 256 + d * 16 + e]);
            }
            out[idx] = f2b(acc);
        }
    }
}

// ---------------------------------------------------------------------------
// K4: rowptr (inline partial rescan) | fixHB | zero fillpos.
// ---------------------------------------------------------------------------
__global__ __launch_bounds__(256) void k4_kernel(const int* __restrict__ tmp,
                                                 const int* __restrict__ part,
                                                 int* __restrict__ rowptr,
                                                 int* __restrict__ HB,
                                                 const int* __restrict__ CS,
                                                 int* __restrict__ fillpos) {
    const int b = blockIdx.x;
    if (b < NSCB) {
        __shared__ int ls[256];
        const int t = threadIdx.x;
        ls[t] = (t < 109) ? part[t] : 0;
        __syncthreads();
        for (int off = 1; off < 256; off <<= 1) {
            int y = (t >= off) ? ls[t - off] : 0;
            __syncthreads();
            ls[t] += y;
            __syncthreads();
        }
        int i = b * 256 + t;
        if (i <= NC)
            rowptr[i] = (i == NC) ? ls[255] : tmp[i] + ((i >> 10) ? ls[(i >> 10) - 1] : 0);
    } else if (b < NSCB + 188) {
        int g = (b - NSCB) * 256 + threadIdx.x;
        int idx0, step;
        if (!cs_geom(g, idx0, step)) return;
        int run = CS[g];
#pragma unroll
        for (int bb = 0; bb < 16; bb++) {
            int t2 = HB[idx0 + bb * step];
            HB[idx0 + bb * step] = run;
            run += t2;
        }
    } else {
        int g = (b - NSCB - 188) * 256 + threadIdx.x;
        if (g < 100000) fillpos[g] = 0;
    }
}

// ---------------------------------------------------------------------------
// qkv: wide Q+KV projections (1658 blocks). Dyn LDS: 50176 B.
// ---------------------------------------------------------------------------
struct QKVArgs {
    const ush* X;
    ush* Q;
    ush* KVk[4];
    ush* KVv[4];
    const ush* Wq[3];  // fragment layout (TW)
    const ush* Bq[3];
    const ush* We[4];  // fragment layout (weff)
};

__global__ __launch_bounds__(256) void qkv_kernel(QKVArgs a) {
    extern __shared__ short smem[];
    const int b = blockIdx.x;
    short* sA = smem;
    short* sB = smem + 64 * 72;
    if (b < 1563) {
        stage_A<64>(sA, a.X, N_P, b * 64);
        gemm_wide<20>(sA, sB, a.Wq[0], a.Bq[0], a.Q,
                      a.We[0], a.KVk[0], a.KVv[0],
                      a.We[3], a.KVk[3], a.KVv[3], N_P, b * 64);
    } else if (b < 1579) {
        int lb = b - 1563;
        stage_A<64>(sA, a.X + (size_t)N_P * 64, N_D, lb * 64);
        gemm_wide<20>(sA, sB, a.Wq[1], a.Bq[1], a.Q + (size_t)N_P * 64,
                      a.We[1], a.KVk[1], a.KVv[1],
                      a.We[2], a.KVk[2], a.KVv[2], N_D, lb * 64);
    } else {
        int lb = b - 1579;
        stage_A<64>(sA, a.X + (size_t)(N_P + N_D) * 64, N_S, lb * 64);
        gemm_wide<4>(sA, sB, a.Wq[2], a.Bq[2], a.Q + (size_t)(N_P + N_D) * 64,
                     nullptr, nullptr, nullptr, nullptr, nullptr, nullptr,
                     N_S, lb * 64);
    }
}

// ---------------------------------------------------------------------------
// fill: CSR column fill (layer 0 only). Dyn LDS: 20000 B.
// ---------------------------------------------------------------------------
struct FillArgs {
    CsrB cb;
    const int* HB;
    const int* rowptr;
    int* fillpos;  // == CNT base; kernel indexes fillpos[1000 + dst]
    int* col;
};

__global__ __launch_bounds__(256) void fill_kernel(FillArgs a) {
    extern __shared__ short smem[];
    const int b = blockIdx.x;
    if (b < NHIST) {
        int* h = (int*)smem;
        int r, E, ndst, e0, e1, hb;
        const int* ei;
        hist_geom(b, a.cb, r, ei, E, ndst, e0, e1, hb);
        const int roff = (r == 0) ? 0 : (r == 1) ? 101000 : 106000;
        for (int d = threadIdx.x; d < ndst; d += 256) h[d] = a.rowptr[roff + d] + a.HB[hb + d];
        __syncthreads();
        for (int e = e0 + threadIdx.x; e < e1; e += 256) {
            int d = ei[E + e];
            int slot = atomicAdd(&h[d], 1);
            a.col[slot] = ei[e];
        }
    } else {
        int g = (b - NHIST) * 256 + threadIdx.x;
        if (g < 300000) {
            int gi = 1000 + a.cb.ei1[300000 + g];
            int slot = a.rowptr[gi] + atomicAdd(&a.fillpos[gi], 1);
            a.col[slot] = a.cb.ei1[g];
        }
    }
}

// ---------------------------------------------------------------------------
// Fused gather aggregation; K/V in split half-arrays; writes gelu(out) bf16.
// Softmax uses a fixed per-lane shift (first edge's alpha) instead of a
// running max: iterations become independent -> loads pipeline. The cross-
// lane (m,s,acc) combine is shift-invariant, so the result is identical
// softmax with a different stabilizer (safe: |alpha| spread << fp32 exp range).
// ---------------------------------------------------------------------------
struct AggrArgs {
    const int* rowptr;
    const int* col;
    const ush* KVk[4];
    const ush* KVv[4];
    const ush* Q;
    const ush* prel;
    ush* OUT;
};

template <int LANES>
__device__ __forceinline__ void seg_attn(const AggrArgs& a, int rel, int g, int h, int lane,
                                         const float* qf, float* o) {
    const int s0 = a.rowptr[g], s1 = a.rowptr[g + 1];
    const ush* Kb = a.KVk[rel];
    const ush* Vb = a.KVv[rel];
    const float ps = b2f(a.prel[rel * 4 + h]) * 0.25f;
    float m = -1e30f, s = 0.f;
    float acc[16];
#pragma unroll
    for (int i = 0; i < 16; i++) acc[i] = 0.f;
    int j = s0 + lane;
    if (j < s1) {
        // peeled first edge: defines the shift; exp(0) = 1
        {
            int src = a.col[j];
            const ush* kp = Kb + (size_t)src * 64 + h * 16;
            const ush* vp = Vb + (size_t)src * 64 + h * 16;
            short8 k0 = *(const short8*)(const void*)kp;
            short8 k1 = *(const short8*)(const void*)(kp + 8);
            short8 v0 = *(const short8*)(const void*)vp;
            short8 v1 = *(const short8*)(const void*)(vp + 8);
            float dot = 0.f;
#pragma unroll
            for (int i = 0; i < 8; i++) dot += qf[i] * b2f((ush)k0[i]);
#pragma unroll
            for (int i = 0; i < 8; i++) dot += qf[8 + i] * b2f((ush)k1[i]);
            m = dot * ps;
            s = 1.f;
#pragma unroll
            for (int i = 0; i < 8; i++) acc[i] = b2f((ush)v0[i]);
#pragma unroll
            for (int i = 0; i < 8; i++) acc[8 + i] = b2f((ush)v1[i]);
        }
        for (j += LANES; j < s1; j += LANES) {
            int src = a.col[j];
            const ush* kp = Kb + (size_t)src * 64 + h * 16;
            const ush* vp = Vb + (size_t)src * 64 + h * 16;
            short8 k0 = *(const short8*)(const void*)kp;
            short8 k1 = *(const short8*)(const void*)(kp + 8);
            short8 v0 = *(const short8*)(const void*)vp;
            short8 v1 = *(const short8*)(const void*)(vp + 8);
            float dot = 0.f;
#pragma unroll
            for (int i = 0; i < 8; i++) dot += qf[i] * b2f((ush)k0[i]);
#pragma unroll
            for (int i = 0; i < 8; i++) dot += qf[8 + i] * b2f((ush)k1[i]);
            float e1 = __expf(dot * ps - m);
            s += e1;
#pragma unroll
            for (int i = 0; i < 8; i++) acc[i] += e1 * b2f((ush)v0[i]);
#pragma unroll
            for (int i = 0; i < 8; i++) acc[8 + i] += e1 * b2f((ush)v1[i]);
        }
    }
#pragma unroll
    for (int wd = LANES >> 1; wd >= 1; wd >>= 1) {
        float mo = __shfl_xor(m, wd);
        float so = __shfl_xor(s, wd);
        float nm = fmaxf(m, mo);
        float e0 = __expf(m - nm), e1 = __expf(mo - nm);
        s = s * e0 + so * e1;
#pragma unroll
        for (int i = 0; i < 16; i++) {
            float ao = __shfl_xor(acc[i], wd);
            acc[i] = acc[i] * e0 + ao * e1;
        }
        m = nm;
    }
    float inv = 1.f / (s + 1e-16f);
#pragma unroll
    for (int i = 0; i < 16; i++) o[i] += acc[i] * inv;
}

template <int LANES>
__device__ __forceinline__ void job_run(const AggrArgs& a, int wid, int nd, int rel, int roff,
                                        size_t xoff, int rel2, int roff2) {
    const int lane = wid % LANES;
    const int grp = wid / LANES;
    const int d = grp >> 2, h = grp & 3;
    if (d >= nd) return;
    const ush* qp = a.Q + xoff + (size_t)d * 64 + h * 16;
    short8 q0 = *(const short8*)(const void*)qp;
    short8 q1 = *(const short8*)(const void*)(qp + 8);
    float qf[16];
#pragma unroll
    for (int i = 0; i < 8; i++) { qf[i] = b2f((ush)q0[i]); qf[8 + i] = b2f((ush)q1[i]); }
    float o[16];
#pragma unroll
    for (int i = 0; i < 16; i++) o[i] = 0.f;
    seg_attn<LANES>(a, rel, roff + d, h, lane, qf, o);
    if (rel2 >= 0) seg_attn<LANES>(a, rel2, roff2 + d, h, lane, qf, o);
    if (lane == 0) {
        ush* op = a.OUT + xoff + (size_t)d * 64 + h * 16;
        short8 w0, w1;
#pragma unroll
        for (int i = 0; i < 8; i++) {
            float va = o[i];
            w0[i] = (short)f2b(0.5f * va * (1.0f + erff(va * 0.70710678118654752f)));
            float vb = o[8 + i];
            w1[i] = (short)f2b(0.5f * vb * (1.0f + erff(vb * 0.70710678118654752f)));
        }
        *(short8*)(op) = w0;
        *(short8*)(op + 8) = w1;
    }
}

// blocks: [0,250) drugs L=16 | [250,563) diseases L=4 | [563,3688) patients L=2
__global__ __launch_bounds__(256) void aggr_kernel(AggrArgs a) {
    const int b = blockIdx.x, t = threadIdx.x;
    if (b < 250) {
        job_run<16>(a, b * 256 + t, N_D, 0, 0, (size_t)N_P * 64, -1, 0);
    } else if (b < 563) {
        job_run<4>(a, (b - 250) * 256 + t, N_S, 2, 101000, (size_t)(N_P + N_D) * 64, 3, 106000);
    } else {
        job_run<2>(a, (b - 563) * 256 + t, N_P, 1, 1000, 0, -1, 0);
    }
}

// ---------------------------------------------------------------------------
// Batched MFMA epilogue: x = s*(OUT @ Wa + ba) + (1-s)*x.  B via fragment
// memcpy staging; blend+store via fp32 LDS chunks (coalesced X read & write).
// ---------------------------------------------------------------------------
struct EpiArgs {
    const ush* O;
    ush* X;
    const ush* W[3];  // fragment layout (TWA)
    const ush* Bb[3];
    const ush* skipv;
    void* fout;
    int foutf;  // 1 = final output fp32, 0 = bf16
    int last;
};

__global__ __launch_bounds__(256) void epi_kernel(EpiArgs a) {
    const int b = blockIdx.x;
    int t, lb, M;
    size_t noff;
    if (b < 1563) { t = 0; lb = b; M = N_P; noff = 0; }
    else if (b < 1579) { t = 1; lb = b - 1563; M = N_D; noff = (size_t)N_P; }
    else { t = 2; lb = b - 1579; M = N_S; noff = (size_t)(N_P + N_D); }
    const ush* O = a.O + noff * 64;
    ush* X = a.X + noff * 64;
    const ush* WF = a.W[t];
    __shared__ short sA[64 * 72];  // 9216 B; reused as fp32 stage (32 x 68 floats)
    __shared__ short sB[8 * 512];
    const int tid = threadIdx.x;
    const int row0 = lb * 64;
    for (int cid = tid; cid < 512; cid += 256) {
        int r = cid >> 3, c0 = (cid & 7) * 8;
        int row = row0 + r;
        short8 sv = {0, 0, 0, 0, 0, 0, 0, 0};
        if (row < M) sv = *(const short8*)(const void*)(O + (size_t)row * 64 + c0);
        *(short8*)(&sA[r * 72 + c0]) = sv;
    }
    for (int u = tid; u < 512; u += 256)
        *(short8*)(&sB[u * 8]) = *(const short8*)(const void*)(WF + (size_t)u * 8);
    __syncthreads();
    const float sg = 1.f / (1.f + expf(-b2f(a.skipv[t])));
    const int w = tid >> 6, l = tid & 63;
    floatx4 acc[4];
#pragma unroll
    for (int c = 0; c < 4; c++) {
        float bv = b2f(a.Bb[t][16 * c + (l & 15)]);
        acc[c] = (floatx4){bv, bv, bv, bv};
    }
#pragma unroll
    for (int s = 0; s < 2; s++) {
        short8 av = *(const short8*)(&sA[(16 * w + (l & 15)) * 72 + 32 * s + ((l >> 4) << 3)]);
#pragma unroll
        for (int c = 0; c < 4; c++) {
            short8 bv = *(const short8*)(&sB[(s * 4 + c) * 512 + l * 8]);
            acc[c] = __builtin_amdgcn_mfma_f32_16x16x32_bf16(av, bv, acc[c], 0, 0, 0);
        }
    }
    float* sOf = (float*)sA;
#pragma unroll
    for (int ch = 0; ch < 2; ch++) {
        __syncthreads();
        if ((w >> 1) == ch) {
#pragma unroll
            for (int c = 0; c < 4; c++)
#pragma unroll
                for (int r = 0; r < 4; r++)
                    sOf[(16 * (w & 1) + ((l >> 4) << 2) + r) * 68 + 16 * c + (l & 15)] =
                        acc[c][r];
        }
        __syncthreads();
        {
            int r = tid >> 3, c0 = (tid & 7) * 8;
            int row = row0 + ch * 32 + r;
            if (row < M) {
                floatx4 f0 = *(const floatx4*)(&sOf[r * 68 + c0]);
                floatx4 f1 = *(const floatx4*)(&sOf[r * 68 + c0 + 4]);
                short8 xv = *(const short8*)(const void*)(X + (size_t)row * 64 + c0);
                float vo[8];
#pragma unroll
                for (int j = 0; j < 4; j++) vo[j] = sg * f0[j] + (1.f - sg) * b2f((ush)xv[j]);
#pragma unroll
                for (int j = 0; j < 4; j++)
                    vo[4 + j] = sg * f1[j] + (1.f - sg) * b2f((ush)xv[4 + j]);
                if (!a.last) {
                    short8 ov;
#pragma unroll
                    for (int j = 0; j < 8; j++) ov[j] = (short)f2b(vo[j]);
                    *(short8*)(X + (size_t)row * 64 + c0) = ov;
                } else {
                    size_t goff = (noff + row) * 64 + c0;
                    if (a.foutf) {
                        floatx4 o0, o1;
#pragma unroll
                        for (int j = 0; j < 4; j++) { o0[j] = vo[j]; o1[j] = vo[4 + j]; }
                        *(floatx4*)((float*)a.fout + goff) = o0;
                        *(floatx4*)((float*)a.fout + goff + 4) = o1;
                    } else {
                        short8 ov;
#pragma unroll
                        for (int j = 0; j < 8; j++) ov[j] = (short)f2b(vo[j]);
                        *(short8*)((ush*)a.fout + goff) = ov;
                    }
                }
            }
        }
    }
}

// ---------------------------------------------------------------------------
extern "C" void kernel_launch(void* const* d_in, const int* in_sizes, int n_in,
                              void* d_out, int out_size, void* d_ws, size_t ws_size,
                              hipStream_t stream) {
    // ---- Workspace layout ----
    char* w = (char*)d_ws;
    w += 64;
    ush* CW = (ush*)w;      w += ((CW_TOTAL * 2 + 63) / 64) * 64;
    ush* WEFFB = (ush*)w;   w += ((size_t)8 * 8320 * 2 + 63) / 64 * 64;
    ush* TW = (ush*)w;      w += (size_t)TW_TOTAL * 2;
    ush* X = (ush*)w;       w += (size_t)NT * 64 * 2;
    ush* Q = (ush*)w;       w += (size_t)NT * 64 * 2;
    ush* KV0 = (ush*)w;     w += (size_t)N_P * 128 * 2;
    ush* KV1 = (ush*)w;     w += (size_t)N_D * 128 * 2;
    ush* KV2 = (ush*)w;     w += (size_t)N_D * 128 * 2;
    ush* KV3 = (ush*)w;     w += (size_t)N_P * 128 * 2;
    ush* OUT = (ush*)w;     w += (size_t)NT * 64 * 4;  // fp32-size slab: HB/CS overlay below
    int* CNT = (int*)w;     w += (size_t)NC * 4;  // r1 region doubles as fillpos
    int* TMP = (int*)w;     w += (size_t)NC * 4;
    int* PART = (int*)w;    w += 512;
    int* ROWPTR = (int*)w;  w += (size_t)(NC + 1) * 4;
    int* COL = (int*)w;     w += (size_t)E_TOT * 4;
    int* HB = (int*)OUT;           // 768000 ints, dead before aggr
    int* CS = (int*)OUT + 800000;  // 48000 ints, same overlay

    // dtype flags from byte sizes (bytes == 2*elems -> bf16, else fp32)
    static const long sz[18] = {4096, 64, 8192, 64, 4096, 64, 24576, 384, 24576, 384,
                                24576, 384, 24576, 384, 8192, 8192, 32, 6};
    ConvArgs ca;
    long cum = 0;
    for (int t = 0; t < 18; t++) {
        ca.src[t] = d_in[3 + t];
        ca.cum[t] = cum;
        ca.fl[t] = (in_sizes[3 + t] != (int)(sz[t] * 2)) ? 1 : 0;
        cum += sz[t];
    }
    ca.cum[18] = cum;

    CsrB cb;
    cb.ei[0] = (const int*)d_in[21];
    cb.ei[1] = (const int*)d_in[23];
    cb.ei[2] = (const int*)d_in[24];
    cb.ei1 = (const int*)d_in[22];

    // K1: convert weights | zero CNT r1 | histograms | fragment transposes
    k1_kernel<<<NCONVB + NZB + NHIST + NTWB, 256, 0, stream>>>(ca, CW, TW, CNT + 1000, cb, HB);

    // K2: input projections | chunk-scan | r1 degree counts
    K2Args k2;
    k2.raw[0] = d_in[0]; k2.f[0] = (in_sizes[0] != N_P * 64 * 2) ? 1 : 0;
    k2.raw[1] = d_in[1]; k2.f[1] = (in_sizes[1] != N_D * 128 * 2) ? 1 : 0;
    k2.raw[2] = d_in[2]; k2.f[2] = (in_sizes[2] != N_S * 64 * 2) ? 1 : 0;
    k2.W[0] = TW + TWINP; k2.Bb[0] = CW + OFF_BINP;
    k2.W[1] = TW + TWIND; k2.Bb[1] = CW + OFF_BIND;
    k2.W[2] = TW + TWINS; k2.Bb[2] = CW + OFF_BINS;
    k2.X = X;
    k2.HB = HB; k2.CS = CS; k2.cnt = CNT; k2.ei1 = cb.ei1;
    k2_kernel<<<1701 + NBLK_R1, 256, 33792, stream>>>(k2);

    // K3: scanA | eff folding (fragment layout)
    k3_kernel<<<109 + 8, 256, 0, stream>>>(CNT, TMP, PART, CW, WEFFB);

    // K4: rowptr | fixHB | zero fillpos
    k4_kernel<<<NSCB + 188 + NZB, 256, 0, stream>>>(TMP, PART, ROWPTR, HB, CS, CNT + 1000);

    ush* KVr[4] = {KV0, KV1, KV2, KV3};
    const size_t nsr[4] = {(size_t)N_P, (size_t)N_D, (size_t)N_D, (size_t)N_P};
    const int foutf = (out_size != NT * 64 * 2) ? 1 : 0;

    for (int l = 0; l < 2; l++) {
        QKVArgs qk;
        qk.X = X;
        qk.Q = Q;
        for (int r = 0; r < 4; r++) {
            qk.KVk[r] = KVr[r];
            qk.KVv[r] = KVr[r] + nsr[r] * 64;
            qk.We[r] = WEFFB + (size_t)(l * 4 + r) * 8320;
        }
        for (int t = 0; t < 3; t++) {
            qk.Wq[t] = TW + TWQO + (size_t)(l * 3 + t) * 4096;
            qk.Bq[t] = CW + OFF_BQ + (l * 3 + t) * 64;
        }
        qkv_kernel<<<1658, 256, 50176, stream>>>(qk);

        if (l == 0) {
            FillArgs fa;
            fa.cb = cb;
            fa.HB = HB;
            fa.rowptr = ROWPTR;
            fa.fillpos = CNT;  // kernel indexes fillpos[1000+dst] -> CNT[1000..101000)
            fa.col = COL;
            fill_kernel<<<NHIST + NBLK_R1, 256, 20000, stream>>>(fa);
        }

        AggrArgs aa;
        aa.rowptr = ROWPTR;
        aa.col = COL;
        for (int r = 0; r < 4; r++) {
            aa.KVk[r] = KVr[r];
            aa.KVv[r] = KVr[r] + nsr[r] * 64;
        }
        aa.Q = Q;
        aa.prel = CW + OFF_PREL + l * 16;
        aa.OUT = OUT;
        aggr_kernel<<<3688, 256, 0, stream>>>(aa);

        EpiArgs ea;
        ea.O = OUT;
        ea.X = X;
        for (int t = 0; t < 3; t++) {
            ea.W[t] = TW + TWAO + (size_t)(l * 3 + t) * 4096;
            ea.Bb[t] = CW + OFF_BA + (l * 3 + t) * 64;
        }
        ea.skipv = CW + OFF_SKIP + l * 3;
        ea.fout = d_out;
        ea.foutf = foutf;
        ea.last = (l == 1) ? 1 : 0;
        epi_kernel<<<1658, 256, 0, stream>>>(ea);
    }
}

// Round 7
// 358.947 us; speedup vs baseline: 1.0754x; 1.0754x over previous
//
#include <hip/hip_runtime.h>
#include <cmath>

typedef unsigned short ush;  // bf16 raw bits
typedef __attribute__((ext_vector_type(8))) short short8;
typedef __attribute__((ext_vector_type(4))) float floatx4;

static constexpr int N_P = 100000, N_D = 1000, N_S = 5000, NT = N_P + N_D + N_S;
static constexpr int NC = 111000;  // concatenated dst slots: r0:1000 | r1:100000 | r2:5000 | r3:5000
static constexpr int E_TOT = 800000;

// hist-CSR geometry
static constexpr int NB0 = 128, NB2 = 64, NB3 = 64;
static constexpr int CH0 = (300000 + NB0 - 1) / NB0;  // 2344
static constexpr int CH2 = (100000 + NB2 - 1) / NB2;  // 1563
static constexpr int HB0_OFF = 0;
static constexpr int HB2_OFF = NB0 * 1000;            // 128000
static constexpr int HB3_OFF = HB2_OFF + NB2 * 5000;  // 448000 -> total 768000
static constexpr int NCH0 = NB0 / 16, NCH2 = NB2 / 16;  // 8, 4
static constexpr int CS0_OFF = 0;
static constexpr int CS2_OFF = NCH0 * 1000;            // 8000
static constexpr int CS3_OFF = CS2_OFF + NCH2 * 5000;  // 28000 -> total 48000
static constexpr int NHIST = NB0 + NB2 + NB3;          // 256
static constexpr int NBLK_R1 = (300000 + 255) / 256;   // 1172
static constexpr int NZB = (100000 + 255) / 256;       // 391

__device__ __forceinline__ float b2f(ush b) { return __uint_as_float(((unsigned)b) << 16); }
__device__ __forceinline__ ush f2b(float f) {
    unsigned u = __float_as_uint(f);
    return (ush)((u + 0x7FFFu + ((u >> 16) & 1u)) >> 16);
}

// canonical weight-block offsets (bf16 elements), d_in[3..20]
static constexpr size_t OFF_WINP = 0;
static constexpr size_t OFF_BINP = 4096;
static constexpr size_t OFF_WIND = 4160;
static constexpr size_t OFF_BIND = 12352;
static constexpr size_t OFF_WINS = 12416;
static constexpr size_t OFF_BINS = 16512;
static constexpr size_t OFF_WK = 16576;
static constexpr size_t OFF_BK = 41152;
static constexpr size_t OFF_WQ = 41536;
static constexpr size_t OFF_BQ = 66112;
static constexpr size_t OFF_WV = 66496;
static constexpr size_t OFF_BV = 91072;
static constexpr size_t OFF_WA = 91456;
static constexpr size_t OFF_BA = 116032;
static constexpr size_t OFF_AREL = 116416;
static constexpr size_t OFF_MREL = 124608;
static constexpr size_t OFF_PREL = 132800;
static constexpr size_t OFF_SKIP = 132832;
static constexpr size_t CW_TOTAL = 132838;
static constexpr int NCONVB = (int)((CW_TOTAL + 255) / 256);  // 519
static constexpr int NSCB = (NC + 1 + 255) / 256;             // 434

// fragment-layout weight buffer (ush elements)
static constexpr size_t TWINP = 0;      // 4096  (64x64)
static constexpr size_t TWIND = 4096;   // 8192  (128x64)
static constexpr size_t TWINS = 12288;  // 4096
static constexpr size_t TWQO = 16384;   // 6*4096 (l*3+t)
static constexpr size_t TWAO = 40960;   // 6*4096
static constexpr size_t TW_TOTAL = 65536;
static constexpr int NTWB = (int)(TW_TOTAL / 256);  // 256

struct ConvArgs {
    const void* src[18];
    long cum[19];
    int fl[18];  // 1 = fp32 source, 0 = bf16 source (host-derived from in_sizes)
};

struct CsrB {
    const int* ei[3];  // r0, r2, r3 edge arrays
    const int* ei1;    // r1
};

__device__ __forceinline__ void hist_geom(int b, const CsrB& c, int& r, const int*& ei, int& E,
                                          int& ndst, int& e0, int& e1, int& hb) {
    if (b < NB0) {
        r = 0; ei = c.ei[0]; E = 300000; ndst = 1000;
        e0 = b * CH0; hb = HB0_OFF + b * 1000;
    } else if (b < NB0 + NB2) {
        r = 1; ei = c.ei[1]; E = 100000; ndst = 5000;
        e0 = (b - NB0) * CH2; hb = HB2_OFF + (b - NB0) * 5000;
    } else {
        r = 2; ei = c.ei[2]; E = 100000; ndst = 5000;
        e0 = (b - NB0 - NB2) * CH2; hb = HB3_OFF + (b - NB0 - NB2) * 5000;
    }
    e1 = min(E, e0 + ((r == 0) ? CH0 : CH2));
}

__device__ __forceinline__ bool cs_geom(int g, int& idx0, int& step) {
    if (g >= 48000) return false;
    if (g < 8000) {
        int c = g / 1000, d = g % 1000;
        idx0 = HB0_OFF + c * 16 * 1000 + d; step = 1000;
    } else if (g < 28000) {
        int gg = g - 8000, c = gg / 5000, d = gg % 5000;
        idx0 = HB2_OFF + c * 16 * 5000 + d; step = 5000;
    } else {
        int gg = g - 28000, c = gg / 5000, d = gg % 5000;
        idx0 = HB3_OFF + c * 16 * 5000 + d; step = 5000;
    }
    return true;
}

// ---------------------------------------------------------------------------
// K1: convert weights | zero CNT r1 | histograms | fragment-transpose weights.
// Fragment layout for [K][64] weight: frag f = s*4+c holds, for lane l elem j:
//   W[(32s + ((l>>4)<<3) + j)*64 + 16c + (l&15)]   at  TW[f*512 + l*8 + j].
// ---------------------------------------------------------------------------
__global__ __launch_bounds__(256) void k1_kernel(ConvArgs a, ush* __restrict__ dst,
                                                 ush* __restrict__ tw,
                                                 int* __restrict__ cnt_r1, CsrB c,
                                                 int* __restrict__ HB) {
    const int b = blockIdx.x;
    if (b < NCONVB) {
        long g = (long)b * 256 + threadIdx.x;
        if (g >= (long)CW_TOTAL) return;
        int t = 0;
        while (g >= a.cum[t + 1]) t++;
        long i = g - a.cum[t];
        float v = a.fl[t] ? ((const float*)a.src[t])[i] : b2f(((const ush*)a.src[t])[i]);
        dst[g] = f2b(v);
    } else if (b < NCONVB + NZB) {
        int g = (b - NCONVB) * 256 + threadIdx.x;
        if (g < 100000) cnt_r1[g] = 0;
    } else if (b < NCONVB + NZB + NHIST) {
        __shared__ int h[5000];
        int r, E, ndst, e0, e1, hb;
        const int* ei;
        hist_geom(b - NCONVB - NZB, c, r, ei, E, ndst, e0, e1, hb);
        for (int d = threadIdx.x; d < ndst; d += 256) h[d] = 0;
        __syncthreads();
        for (int e = e0 + threadIdx.x; e < e1; e += 256) atomicAdd(&h[ei[E + e]], 1);
        __syncthreads();
        for (int d = threadIdx.x; d < ndst; d += 256) HB[hb + d] = h[d];
    } else {
        int g = (b - NCONVB - NZB - NHIST) * 256 + threadIdx.x;  // [0, 65536)
        const void* src; int fl; long ibase; int e;
        if (g < 4096) { src = a.src[0]; fl = a.fl[0]; e = g; ibase = 0; }
        else if (g < 12288) { src = a.src[2]; fl = a.fl[2]; e = g - 4096; ibase = 0; }
        else if (g < 16384) { src = a.src[4]; fl = a.fl[4]; e = g - 12288; ibase = 0; }
        else if (g < 40960) { int ee = g - 16384; src = a.src[8]; fl = a.fl[8];
                              e = ee & 4095; ibase = (long)(ee >> 12) * 4096; }
        else { int ee = g - 40960; src = a.src[12]; fl = a.fl[12];
               e = ee & 4095; ibase = (long)(ee >> 12) * 4096; }
        int f = e >> 9, l = (e >> 3) & 63, j = e & 7;
        int s = f >> 2, cc = f & 3;
        long in = ibase + (long)(32 * s + ((l >> 4) << 3) + j) * 64 + 16 * cc + (l & 15);
        float v = fl ? ((const float*)src)[in] : b2f(((const ush*)src)[in]);
        tw[g] = f2b(v);
    }
}

// ---------------------------------------------------------------------------
// MFMA building blocks: memcpy B-staging from fragment-layout weights,
// LDS-staged coalesced output stores.
// ---------------------------------------------------------------------------
template <int K>
__device__ __forceinline__ void stage_A(short* sA, const ush* __restrict__ X, int M, int row0) {
    for (int cid = threadIdx.x; cid < 64 * K / 8; cid += 256) {
        int r = cid / (K / 8), c0 = (cid % (K / 8)) * 8;
        int row = row0 + r;
        short8 v = {0, 0, 0, 0, 0, 0, 0, 0};
        if (row < M) v = *(const short8*)(const void*)(X + (size_t)row * K + c0);
        *(short8*)(&sA[r * (K + 8) + c0]) = v;
    }
}

template <int K>
__device__ __forceinline__ void stage_A_raw(short* sA, const void* __restrict__ X, int f,
                                            int M, int row0) {
    for (int cid = threadIdx.x; cid < 64 * K / 8; cid += 256) {
        int r = cid / (K / 8), c0 = (cid % (K / 8)) * 8;
        int row = row0 + r;
        short8 v = {0, 0, 0, 0, 0, 0, 0, 0};
        if (row < M) {
            if (f) {
                const floatx4* fp = (const floatx4*)((const float*)X + (size_t)row * K + c0);
                floatx4 f0 = fp[0], f1 = fp[1];
#pragma unroll
                for (int j = 0; j < 4; j++) v[j] = (short)f2b(f0[j]);
#pragma unroll
                for (int j = 0; j < 4; j++) v[4 + j] = (short)f2b(f1[j]);
            } else {
                v = *(const short8*)(const void*)((const ush*)X + (size_t)row * K + c0);
            }
        }
        *(short8*)(&sA[r * (K + 8) + c0]) = v;
    }
}

// W is fragment-layout. Output 64x64, staged through sB region (free after MFMA).
template <int K>
__device__ __forceinline__ void gemm_core64(const short* sA, short* sB,
                                            const ush* __restrict__ W, const ush* __restrict__ Bb,
                                            ush* __restrict__ Y, int M, int row0) {
    constexpr int NF = (K / 32) * 4;
    const int tid = threadIdx.x;
    for (int u = tid; u < NF * 64; u += 256)
        *(short8*)(&sB[u * 8]) = *(const short8*)(const void*)(W + (size_t)u * 8);
    __syncthreads();
    const int w = tid >> 6, l = tid & 63;
    floatx4 acc[4];
#pragma unroll
    for (int c = 0; c < 4; c++) {
        float bv = b2f(Bb[16 * c + (l & 15)]);
        acc[c] = (floatx4){bv, bv, bv, bv};
    }
#pragma unroll
    for (int s = 0; s < K / 32; s++) {
        short8 a = *(const short8*)(&sA[(16 * w + (l & 15)) * (K + 8) + 32 * s + ((l >> 4) << 3)]);
#pragma unroll
        for (int c = 0; c < 4; c++) {
            short8 b = *(const short8*)(&sB[(s * 4 + c) * 512 + l * 8]);
            acc[c] = __builtin_amdgcn_mfma_f32_16x16x32_bf16(a, b, acc[c], 0, 0, 0);
        }
    }
    __syncthreads();
#pragma unroll
    for (int c = 0; c < 4; c++)
#pragma unroll
        for (int r = 0; r < 4; r++)
            sB[(16 * w + ((l >> 4) << 2) + r) * 72 + 16 * c + (l & 15)] =
                (short)f2b(acc[c][r]);
    __syncthreads();
    for (int u = tid; u < 512; u += 256) {
        int r = u >> 3, c0 = (u & 7) * 8;
        int row = row0 + r;
        if (row < M)
            *(short8*)(Y + (size_t)row * 64 + c0) = *(const short8*)(&sB[r * 72 + c0]);
    }
}

// ---------------------------------------------------------------------------
// 5-panel streaming QKV gemm: A-fragments in registers (sA freed -> output
// stage), per panel {stage 8KB B, 8 MFMAs, scatter, coalesced store}.
// LDS: sA 9216 B + sB 8192 B = 17408 B -> 8+ blocks/CU (vs 3 at 50KB).
// Panels: 0=Q, 1=relA.K, 2=relA.V, 3=relB.K, 4=relB.V (all ld-64).
// ---------------------------------------------------------------------------
template <int NP>
__device__ __forceinline__ void gemm_panels(short* sA, short* sB,
                                            const ush* __restrict__ Wq,
                                            const ush* __restrict__ Bq, ush* __restrict__ Yq,
                                            const ush* __restrict__ WeA,
                                            ush* __restrict__ YAk, ush* __restrict__ YAv,
                                            const ush* __restrict__ WeB,
                                            ush* __restrict__ YBk, ush* __restrict__ YBv,
                                            int M, int row0) {
    const int tid = threadIdx.x;
    const int w = tid >> 6, l = tid & 63;
    __syncthreads();  // stage_A visible
    short8 a0 = *(const short8*)(&sA[(16 * w + (l & 15)) * 72 + ((l >> 4) << 3)]);
    short8 a1 = *(const short8*)(&sA[(16 * w + (l & 15)) * 72 + 32 + ((l >> 4) << 3)]);
    ush* dst[5] = {Yq, YAk, YAv, YBk, YBv};
#pragma unroll
    for (int p = 0; p < NP; p++) {
        __syncthreads();  // prev MFMA done with sB; prev store done with sA-out; a-regs loaded
        const ush* base = (p == 0) ? Wq : ((p <= 2) ? WeA : WeB);
        const int nw = (p == 0) ? 4 : 8;
        const int moff = (p == 0 || p == 1 || p == 3) ? 0 : 4;
        for (int u = tid; u < 512; u += 256) {
            int f = u >> 6, k = u & 63;  // f = s*4 + c
            int s = f >> 2, c = f & 3;
            const ush* src = base + (size_t)(s * nw + moff + c) * 512;
            *(short8*)(&sB[f * 512 + k * 8]) = *(const short8*)(const void*)(src + k * 8);
        }
        __syncthreads();
        const ush* bias = (p == 0) ? Bq : ((p <= 2) ? WeA + 8192 : WeB + 8192);
        const int boff = (p == 0 || p == 1 || p == 3) ? 0 : 64;
        floatx4 acc[4];
#pragma unroll
        for (int c = 0; c < 4; c++) {
            float bv = b2f(bias[boff + 16 * c + (l & 15)]);
            acc[c] = (floatx4){bv, bv, bv, bv};
        }
#pragma unroll
        for (int c = 0; c < 4; c++) {
            short8 b0 = *(const short8*)(&sB[c * 512 + l * 8]);
            acc[c] = __builtin_amdgcn_mfma_f32_16x16x32_bf16(a0, b0, acc[c], 0, 0, 0);
            short8 b1 = *(const short8*)(&sB[(4 + c) * 512 + l * 8]);
            acc[c] = __builtin_amdgcn_mfma_f32_16x16x32_bf16(a1, b1, acc[c], 0, 0, 0);
        }
        // scatter to sA-out (prev store reads finished before this panel's top barrier)
#pragma unroll
        for (int c = 0; c < 4; c++)
#pragma unroll
            for (int r = 0; r < 4; r++)
                sA[(16 * w + ((l >> 4) << 2) + r) * 72 + 16 * c + (l & 15)] =
                    (short)f2b(acc[c][r]);
        __syncthreads();
        ush* Y = dst[p];
        for (int u = tid; u < 512; u += 256) {
            int r = u >> 3, c0 = (u & 7) * 8;
            int row = row0 + r;
            if (row < M)
                *(short8*)(Y + (size_t)row * 64 + c0) = *(const short8*)(&sA[r * 72 + c0]);
        }
    }
}

// ---------------------------------------------------------------------------
// K2: fused input projections | chunk-scan | r1 counts. Dyn LDS: 33792 B.
// ---------------------------------------------------------------------------
struct K2Args {
    const void* raw[3];
    int f[3];
    const ush* W[3];   // fragment layout (TW)
    const ush* Bb[3];
    ush* X;
    const int* HB;
    int* CS;
    int* cnt;
    const int* ei1;
};

__global__ __launch_bounds__(256) void k2_kernel(K2Args a) {
    extern __shared__ short smem[];
    const int b = blockIdx.x;
    if (b < 1658) {
        if (b < 1563) {
            short* sA = smem; short* sB = smem + 64 * 72;
            stage_A_raw<64>(sA, a.raw[0], a.f[0], N_P, b * 64);
            gemm_core64<64>(sA, sB, a.W[0], a.Bb[0], a.X, N_P, b * 64);
        } else if (b < 1579) {
            short* sA = smem; short* sB = smem + 64 * 136;
            stage_A_raw<128>(sA, a.raw[1], a.f[1], N_D, (b - 1563) * 64);
            gemm_core64<128>(sA, sB, a.W[1], a.Bb[1], a.X + (size_t)N_P * 64, N_D,
                             (b - 1563) * 64);
        } else {
            short* sA = smem; short* sB = smem + 64 * 72;
            stage_A_raw<64>(sA, a.raw[2], a.f[2], N_S, (b - 1579) * 64);
            gemm_core64<64>(sA, sB, a.W[2], a.Bb[2], a.X + (size_t)(N_P + N_D) * 64, N_S,
                            (b - 1579) * 64);
        }
    } else if (b < 1701) {
        int d = (b - 1658) * 256 + threadIdx.x;
        if (d >= 11000) return;
        int ld_, nch, base, step, cs0, csstep, roff;
        if (d < 1000) { ld_ = d; nch = NCH0; base = HB0_OFF + ld_; step = 1000;
                        cs0 = CS0_OFF + ld_; csstep = 1000; roff = 0; }
        else if (d < 6000) { ld_ = d - 1000; nch = NCH2; base = HB2_OFF + ld_; step = 5000;
                             cs0 = CS2_OFF + ld_; csstep = 5000; roff = 101000; }
        else { ld_ = d - 6000; nch = NCH2; base = HB3_OFF + ld_; step = 5000;
               cs0 = CS3_OFF + ld_; csstep = 5000; roff = 106000; }
        int run = 0;
        for (int cc = 0; cc < nch; cc++) {
            int s = 0;
#pragma unroll
            for (int bb = 0; bb < 16; bb++) s += a.HB[base + (cc * 16 + bb) * step];
            a.CS[cs0 + cc * csstep] = run;
            run += s;
        }
        a.cnt[roff + ld_] = run;
    } else {
        int g = (b - 1701) * 256 + threadIdx.x;
        if (g < 300000) atomicAdd(&a.cnt[1000 + a.ei1[300000 + g]], 1);
    }
}

// ---------------------------------------------------------------------------
// K3: scanA | eff weight folding, emitted directly in fragment layout.
// ---------------------------------------------------------------------------
__global__ __launch_bounds__(256) void k3_kernel(const int* __restrict__ cnt,
                                                 int* __restrict__ tmp,
                                                 int* __restrict__ part,
                                                 const ush* __restrict__ CW,
                                                 ush* __restrict__ weff) {
    const int b = blockIdx.x;
    if (b < 109) {
        __shared__ int ls[256];
        const int t = threadIdx.x;
        const int base = b * 1024 + t * 4;
        int v[4];
#pragma unroll
        for (int j = 0; j < 4; j++) v[j] = (base + j < NC) ? cnt[base + j] : 0;
        int tsum = v[0] + v[1] + v[2] + v[3];
        ls[t] = tsum;
        __syncthreads();
        for (int off = 1; off < 256; off <<= 1) {
            int y = (t >= off) ? ls[t - off] : 0;
            __syncthreads();
            ls[t] += y;
            __syncthreads();
        }
        int run = ls[t] - tsum;
#pragma unroll
        for (int j = 0; j < 4; j++) {
            if (base + j < NC) tmp[base + j] = run;
            run += v[j];
        }
        if (t == 255) part[b] = ls[255];
    } else {
        const int eb = b - 109;  // l*4+r
        const int l = eb >> 2, r = eb & 3;
        const int st_of[4] = {0, 1, 1, 0};
        const int st = st_of[r];
        ush* out = weff + (size_t)eb * 8320;
        for (int idx = threadIdx.x; idx < 8320; idx += 256) {
            int k, n;
            if (idx < 8192) {
                int f = idx >> 9, ll = (idx >> 3) & 63, j = idx & 7;
                int s = f >> 3, c = f & 7;
                k = 32 * s + ((ll >> 4) << 3) + j;
                n = 16 * c + (ll & 15);
            } else { k = -1; n = idx - 8192; }
            int kv = n >= 64;
            int jj = n & 63, h = jj >> 4, e = jj & 15;
            const ush* W = CW + (kv ? OFF_WV : OFF_WK) + (size_t)(l * 3 + st) * 4096;
            const ush* B = CW + (kv ? OFF_BV : OFF_BK) + (size_t)(l * 3 + st) * 64;
            const ush* R = CW + (kv ? OFF_MREL : OFF_AREL) + (size_t)(l * 4 + r) * 1024;
            float acc = 0.f;
            if (k >= 0) {
#pragma unroll
                for (int d = 0; d < 16; d++)
                    acc += b2f(W[k * 64 + h * 16 + d]) * b2f(R[h * 256 + d * 16 + e]);
            } else {
#pragma unroll
                for (int d = 0; d < 16; d++)
                    acc += b2f(B[h * 16 + d]) * b2f(R[h * 256 + d * 16 + e]);
            }
            out[idx] = f2b(acc);
        }
    }
}

// ---------------------------------------------------------------------------
// K4: rowptr (inline partial rescan) | fixHB | zero fillpos.
// ---------------------------------------------------------------------------
__global__ __launch_bounds__(256) void k4_kernel(const int* __restrict__ tmp,
                                                 const int* __restrict__ part,
                                                 int* __restrict__ rowptr,
                                                 int* __restrict__ HB,
                                                 const int* __restrict__ CS,
                                                 int* __restrict__ fillpos) {
    const int b = blockIdx.x;
    if (b < NSCB) {
        __shared__ int ls[256];
        const int t = threadIdx.x;
        ls[t] = (t < 109) ? part[t] : 0;
        __syncthreads();
        for (int off = 1; off < 256; off <<= 1) {
            int y = (t >= off) ? ls[t - off] : 0;
            __syncthreads();
            ls[t] += y;
            __syncthreads();
        }
        int i = b * 256 + t;
        if (i <= NC)
            rowptr[i] = (i == NC) ? ls[255] : tmp[i] + ((i >> 10) ? ls[(i >> 10) - 1] : 0);
    } else if (b < NSCB + 188) {
        int g = (b - NSCB) * 256 + threadIdx.x;
        int idx0, step;
        if (!cs_geom(g, idx0, step)) return;
        int run = CS[g];
#pragma unroll
        for (int bb = 0; bb < 16; bb++) {
            int t2 = HB[idx0 + bb * step];
            HB[idx0 + bb * step] = run;
            run += t2;
        }
    } else {
        int g = (b - NSCB - 188) * 256 + threadIdx.x;
        if (g < 100000) fillpos[g] = 0;
    }
}

// ---------------------------------------------------------------------------
// qkv: wide Q+KV projections (1658 blocks). Dyn LDS: 17408 B.
// ---------------------------------------------------------------------------
struct QKVArgs {
    const ush* X;
    ush* Q;
    ush* KVk[4];
    ush* KVv[4];
    const ush* Wq[3];  // fragment layout (TW)
    const ush* Bq[3];
    const ush* We[4];  // fragment layout (weff)
};

__global__ __launch_bounds__(256) void qkv_kernel(QKVArgs a) {
    extern __shared__ short smem[];
    const int b = blockIdx.x;
    short* sA = smem;
    short* sB = smem + 64 * 72;
    if (b < 1563) {
        stage_A<64>(sA, a.X, N_P, b * 64);
        gemm_panels<5>(sA, sB, a.Wq[0], a.Bq[0], a.Q,
                       a.We[0], a.KVk[0], a.KVv[0],
                       a.We[3], a.KVk[3], a.KVv[3], N_P, b * 64);
    } else if (b < 1579) {
        int lb = b - 1563;
        stage_A<64>(sA, a.X + (size_t)N_P * 64, N_D, lb * 64);
        gemm_panels<5>(sA, sB, a.Wq[1], a.Bq[1], a.Q + (size_t)N_P * 64,
                       a.We[1], a.KVk[1], a.KVv[1],
                       a.We[2], a.KVk[2], a.KVv[2], N_D, lb * 64);
    } else {
        int lb = b - 1579;
        stage_A<64>(sA, a.X + (size_t)(N_P + N_D) * 64, N_S, lb * 64);
        gemm_panels<1>(sA, sB, a.Wq[2], a.Bq[2], a.Q + (size_t)(N_P + N_D) * 64,
                       nullptr, nullptr, nullptr, nullptr, nullptr, nullptr,
                       N_S, lb * 64);
    }
}

// ---------------------------------------------------------------------------
// fill: CSR column fill (layer 0 only). Dyn LDS: 20000 B.
// ---------------------------------------------------------------------------
struct FillArgs {
    CsrB cb;
    const int* HB;
    const int* rowptr;
    int* fillpos;  // == CNT base; kernel indexes fillpos[1000 + dst]
    int* col;
};

__global__ __launch_bounds__(256) void fill_kernel(FillArgs a) {
    extern __shared__ short smem[];
    const int b = blockIdx.x;
    if (b < NHIST) {
        int* h = (int*)smem;
        int r, E, ndst, e0, e1, hb;
        const int* ei;
        hist_geom(b, a.cb, r, ei, E, ndst, e0, e1, hb);
        const int roff = (r == 0) ? 0 : (r == 1) ? 101000 : 106000;
        for (int d = threadIdx.x; d < ndst; d += 256) h[d] = a.rowptr[roff + d] + a.HB[hb + d];
        __syncthreads();
        for (int e = e0 + threadIdx.x; e < e1; e += 256) {
            int d = ei[E + e];
            int slot = atomicAdd(&h[d], 1);
            a.col[slot] = ei[e];
        }
    } else {
        int g = (b - NHIST) * 256 + threadIdx.x;
        if (g < 300000) {
            int gi = 1000 + a.cb.ei1[300000 + g];
            int slot = a.rowptr[gi] + atomicAdd(&a.fillpos[gi], 1);
            a.col[slot] = a.cb.ei1[g];
        }
    }
}

// ---------------------------------------------------------------------------
// Fused gather aggregation; K/V in split half-arrays; writes gelu(out) bf16.
// Fixed per-lane shift softmax (peeled first edge) -> independent iterations.
// Regrid: drugs LANES=64 (r0's 77MB gather gets 4x the waves), diseases 16.
// ---------------------------------------------------------------------------
struct AggrArgs {
    const int* rowptr;
    const int* col;
    const ush* KVk[4];
    const ush* KVv[4];
    const ush* Q;
    const ush* prel;
    ush* OUT;
};

template <int LANES>
__device__ __forceinline__ void seg_attn(const AggrArgs& a, int rel, int g, int h, int lane,
                                         const float* qf, float* o) {
    const int s0 = a.rowptr[g], s1 = a.rowptr[g + 1];
    const ush* Kb = a.KVk[rel];
    const ush* Vb = a.KVv[rel];
    const float ps = b2f(a.prel[rel * 4 + h]) * 0.25f;
    float m = -1e30f, s = 0.f;
    float acc[16];
#pragma unroll
    for (int i = 0; i < 16; i++) acc[i] = 0.f;
    int j = s0 + lane;
    if (j < s1) {
        // peeled first edge: defines the shift; exp(0) = 1
        {
            int src = a.col[j];
            const ush* kp = Kb + (size_t)src * 64 + h * 16;
            const ush* vp = Vb + (size_t)src * 64 + h * 16;
            short8 k0 = *(const short8*)(const void*)kp;
            short8 k1 = *(const short8*)(const void*)(kp + 8);
            short8 v0 = *(const short8*)(const void*)vp;
            short8 v1 = *(const short8*)(const void*)(vp + 8);
            float dot = 0.f;
#pragma unroll
            for (int i = 0; i < 8; i++) dot += qf[i] * b2f((ush)k0[i]);
#pragma unroll
            for (int i = 0; i < 8; i++) dot += qf[8 + i] * b2f((ush)k1[i]);
            m = dot * ps;
            s = 1.f;
#pragma unroll
            for (int i = 0; i < 8; i++) acc[i] = b2f((ush)v0[i]);
#pragma unroll
            for (int i = 0; i < 8; i++) acc[8 + i] = b2f((ush)v1[i]);
        }
        for (j += LANES; j < s1; j += LANES) {
            int src = a.col[j];
            const ush* kp = Kb + (size_t)src * 64 + h * 16;
            const ush* vp = Vb + (size_t)src * 64 + h * 16;
            short8 k0 = *(const short8*)(const void*)kp;
            short8 k1 = *(const short8*)(const void*)(kp + 8);
            short8 v0 = *(const short8*)(const void*)vp;
            short8 v1 = *(const short8*)(const void*)(vp + 8);
            float dot = 0.f;
#pragma unroll
            for (int i = 0; i < 8; i++) dot += qf[i] * b2f((ush)k0[i]);
#pragma unroll
            for (int i = 0; i < 8; i++) dot += qf[8 + i] * b2f((ush)k1[i]);
            float e1 = __expf(dot * ps - m);
            s += e1;
#pragma unroll
            for (int i = 0; i < 8; i++) acc[i] += e1 * b2f((ush)v0[i]);
#pragma unroll
            for (int i = 0; i < 8; i++) acc[8 + i] += e1 * b2f((ush)v1[i]);
        }
    }
#pragma unroll
    for (int wd = LANES >> 1; wd >= 1; wd >>= 1) {
        float mo = __shfl_xor(m, wd);
        float so = __shfl_xor(s, wd);
        float nm = fmaxf(m, mo);
        float e0 = __expf(m - nm), e1 = __expf(mo - nm);
        s = s * e0 + so * e1;
#pragma unroll
        for (int i = 0; i < 16; i++) {
            float ao = __shfl_xor(acc[i], wd);
            acc[i] = acc[i] * e0 + ao * e1;
        }
        m = nm;
    }
    float inv = 1.f / (s + 1e-16f);
#pragma unroll
    for (int i = 0; i < 16; i++) o[i] += acc[i] * inv;
}

template <int LANES>
__device__ __forceinline__ void job_run(const AggrArgs& a, int wid, int nd, int rel, int roff,
                                        size_t xoff, int rel2, int roff2) {
    const int lane = wid % LANES;
    const int grp = wid / LANES;
    const int d = grp >> 2, h = grp & 3;
    if (d >= nd) return;
    const ush* qp = a.Q + xoff + (size_t)d * 64 + h * 16;
    short8 q0 = *(const short8*)(const void*)qp;
    short8 q1 = *(const short8*)(const void*)(qp + 8);
    float qf[16];
#pragma unroll
    for (int i = 0; i < 8; i++) { qf[i] = b2f((ush)q0[i]); qf[8 + i] = b2f((ush)q1[i]); }
    float o[16];
#pragma unroll
    for (int i = 0; i < 16; i++) o[i] = 0.f;
    seg_attn<LANES>(a, rel, roff + d, h, lane, qf, o);
    if (rel2 >= 0) seg_attn<LANES>(a, rel2, roff2 + d, h, lane, qf, o);
    if (lane == 0) {
        ush* op = a.OUT + xoff + (size_t)d * 64 + h * 16;
        short8 w0, w1;
#pragma unroll
        for (int i = 0; i < 8; i++) {
            float va = o[i];
            w0[i] = (short)f2b(0.5f * va * (1.0f + erff(va * 0.70710678118654752f)));
            float vb = o[8 + i];
            w1[i] = (short)f2b(0.5f * vb * (1.0f + erff(vb * 0.70710678118654752f)));
        }
        *(short8*)(op) = w0;
        *(short8*)(op + 8) = w1;
    }
}

// blocks: [0,1000) drugs L=64 | [1000,2250) diseases L=16 | [2250,5375) patients L=2
__global__ __launch_bounds__(256) void aggr_kernel(AggrArgs a) {
    const int b = blockIdx.x, t = threadIdx.x;
    if (b < 1000) {
        job_run<64>(a, b * 256 + t, N_D, 0, 0, (size_t)N_P * 64, -1, 0);
    } else if (b < 2250) {
        job_run<16>(a, (b - 1000) * 256 + t, N_S, 2, 101000, (size_t)(N_P + N_D) * 64, 3, 106000);
    } else {
        job_run<2>(a, (b - 2250) * 256 + t, N_P, 1, 1000, 0, -1, 0);
    }
}

// ---------------------------------------------------------------------------
// Batched MFMA epilogue: x = s*(OUT @ Wa + ba) + (1-s)*x.  B via fragment
// memcpy staging; blend+store via fp32 LDS chunks (coalesced X read & write).
// ---------------------------------------------------------------------------
struct EpiArgs {
    const ush* O;
    ush* X;
    const ush* W[3];  // fragment layout (TWA)
    const ush* Bb[3];
    const ush* skipv;
    void* fout;
    int foutf;  // 1 = final output fp32, 0 = bf16
    int last;
};

__global__ __launch_bounds__(256) void epi_kernel(EpiArgs a) {
    const int b = blockIdx.x;
    int t, lb, M;
    size_t noff;
    if (b < 1563) { t = 0; lb = b; M = N_P; noff = 0; }
    else if (b < 1579) { t = 1; lb = b - 1563; M = N_D; noff = (size_t)N_P; }
    else { t = 2; lb = b - 1579; M = N_S; noff = (size_t)(N_P + N_D); }
    const ush* O = a.O + noff * 64;
    ush* X = a.X + noff * 64;
    const ush* WF = a.W[t];
    __shared__ short sA[64 * 72];  // 9216 B; reused as fp32 stage (32 x 68 floats)
    __shared__ short sB[8 * 512];
    const int tid = threadIdx.x;
    const int row0 = lb * 64;
    for (int cid = tid; cid < 512; cid += 256) {
        int r = cid >> 3, c0 = (cid & 7) * 8;
        int row = row0 + r;
        short8 sv = {0, 0, 0, 0, 0, 0, 0, 0};
        if (row < M) sv = *(const short8*)(const void*)(O + (size_t)row * 64 + c0);
        *(short8*)(&sA[r * 72 + c0]) = sv;
    }
    for (int u = tid; u < 512; u += 256)
        *(short8*)(&sB[u * 8]) = *(const short8*)(const void*)(WF + (size_t)u * 8);
    __syncthreads();
    const float sg = 1.f / (1.f + expf(-b2f(a.skipv[t])));
    const int w = tid >> 6, l = tid & 63;
    floatx4 acc[4];
#pragma unroll
    for (int c = 0; c < 4; c++) {
        float bv = b2f(a.Bb[t][16 * c + (l & 15)]);
        acc[c] = (floatx4){bv, bv, bv, bv};
    }
#pragma unroll
    for (int s = 0; s < 2; s++) {
        short8 av = *(const short8*)(&sA[(16 * w + (l & 15)) * 72 + 32 * s + ((l >> 4) << 3)]);
#pragma unroll
        for (int c = 0; c < 4; c++) {
            short8 bv = *(const short8*)(&sB[(s * 4 + c) * 512 + l * 8]);
            acc[c] = __builtin_amdgcn_mfma_f32_16x16x32_bf16(av, bv, acc[c], 0, 0, 0);
        }
    }
    float* sOf = (float*)sA;
#pragma unroll
    for (int ch = 0; ch < 2; ch++) {
        __syncthreads();
        if ((w >> 1) == ch) {
#pragma unroll
            for (int c = 0; c < 4; c++)
#pragma unroll
                for (int r = 0; r < 4; r++)
                    sOf[(16 * (w & 1) + ((l >> 4) << 2) + r) * 68 + 16 * c + (l & 15)] =
                        acc[c][r];
        }
        __syncthreads();
        {
            int r = tid >> 3, c0 = (tid & 7) * 8;
            int row = row0 + ch * 32 + r;
            if (row < M) {
                floatx4 f0 = *(const floatx4*)(&sOf[r * 68 + c0]);
                floatx4 f1 = *(const floatx4*)(&sOf[r * 68 + c0 + 4]);
                short8 xv = *(const short8*)(const void*)(X + (size_t)row * 64 + c0);
                float vo[8];
#pragma unroll
                for (int j = 0; j < 4; j++) vo[j] = sg * f0[j] + (1.f - sg) * b2f((ush)xv[j]);
#pragma unroll
                for (int j = 0; j < 4; j++)
                    vo[4 + j] = sg * f1[j] + (1.f - sg) * b2f((ush)xv[4 + j]);
                if (!a.last) {
                    short8 ov;
#pragma unroll
                    for (int j = 0; j < 8; j++) ov[j] = (short)f2b(vo[j]);
                    *(short8*)(X + (size_t)row * 64 + c0) = ov;
                } else {
                    size_t goff = (noff + row) * 64 + c0;
                    if (a.foutf) {
                        floatx4 o0, o1;
#pragma unroll
                        for (int j = 0; j < 4; j++) { o0[j] = vo[j]; o1[j] = vo[4 + j]; }
                        *(floatx4*)((float*)a.fout + goff) = o0;
                        *(floatx4*)((float*)a.fout + goff + 4) = o1;
                    } else {
                        short8 ov;
#pragma unroll
                        for (int j = 0; j < 8; j++) ov[j] = (short)f2b(vo[j]);
                        *(short8*)((ush*)a.fout + goff) = ov;
                    }
                }
            }
        }
    }
}

// ---------------------------------------------------------------------------
extern "C" void kernel_launch(void* const* d_in, const int* in_sizes, int n_in,
                              void* d_out, int out_size, void* d_ws, size_t ws_size,
                              hipStream_t stream) {
    // ---- Workspace layout ----
    char* w = (char*)d_ws;
    w += 64;
    ush* CW = (ush*)w;      w += ((CW_TOTAL * 2 + 63) / 64) * 64;
    ush* WEFFB = (ush*)w;   w += ((size_t)8 * 8320 * 2 + 63) / 64 * 64;
    ush* TW = (ush*)w;      w += (size_t)TW_TOTAL * 2;
    ush* X = (ush*)w;       w += (size_t)NT * 64 * 2;
    ush* Q = (ush*)w;       w += (size_t)NT * 64 * 2;
    ush* KV0 = (ush*)w;     w += (size_t)N_P * 128 * 2;
    ush* KV1 = (ush*)w;     w += (size_t)N_D * 128 * 2;
    ush* KV2 = (ush*)w;     w += (size_t)N_D * 128 * 2;
    ush* KV3 = (ush*)w;     w += (size_t)N_P * 128 * 2;
    ush* OUT = (ush*)w;     w += (size_t)NT * 64 * 4;  // fp32-size slab: HB/CS overlay below
    int* CNT = (int*)w;     w += (size_t)NC * 4;  // r1 region doubles as fillpos
    int* TMP = (int*)w;     w += (size_t)NC * 4;
    int* PART = (int*)w;    w += 512;
    int* ROWPTR = (int*)w;  w += (size_t)(NC + 1) * 4;
    int* COL = (int*)w;     w += (size_t)E_TOT * 4;
    int* HB = (int*)OUT;           // 768000 ints, dead before aggr
    int* CS = (int*)OUT + 800000;  // 48000 ints, same overlay

    // dtype flags from byte sizes (bytes == 2*elems -> bf16, else fp32)
    static const long sz[18] = {4096, 64, 8192, 64, 4096, 64, 24576, 384, 24576, 384,
                                24576, 384, 24576, 384, 8192, 8192, 32, 6};
    ConvArgs ca;
    long cum = 0;
    for (int t = 0; t < 18; t++) {
        ca.src[t] = d_in[3 + t];
        ca.cum[t] = cum;
        ca.fl[t] = (in_sizes[3 + t] != (int)(sz[t] * 2)) ? 1 : 0;
        cum += sz[t];
    }
    ca.cum[18] = cum;

    CsrB cb;
    cb.ei[0] = (const int*)d_in[21];
    cb.ei[1] = (const int*)d_in[23];
    cb.ei[2] = (const int*)d_in[24];
    cb.ei1 = (const int*)d_in[22];

    // K1: convert weights | zero CNT r1 | histograms | fragment transposes
    k1_kernel<<<NCONVB + NZB + NHIST + NTWB, 256, 0, stream>>>(ca, CW, TW, CNT + 1000, cb, HB);

    // K2: input projections | chunk-scan | r1 degree counts
    K2Args k2;
    k2.raw[0] = d_in[0]; k2.f[0] = (in_sizes[0] != N_P * 64 * 2) ? 1 : 0;
    k2.raw[1] = d_in[1]; k2.f[1] = (in_sizes[1] != N_D * 128 * 2) ? 1 : 0;
    k2.raw[2] = d_in[2]; k2.f[2] = (in_sizes[2] != N_S * 64 * 2) ? 1 : 0;
    k2.W[0] = TW + TWINP; k2.Bb[0] = CW + OFF_BINP;
    k2.W[1] = TW + TWIND; k2.Bb[1] = CW + OFF_BIND;
    k2.W[2] = TW + TWINS; k2.Bb[2] = CW + OFF_BINS;
    k2.X = X;
    k2.HB = HB; k2.CS = CS; k2.cnt = CNT; k2.ei1 = cb.ei1;
    k2_kernel<<<1701 + NBLK_R1, 256, 33792, stream>>>(k2);

    // K3: scanA | eff folding (fragment layout)
    k3_kernel<<<109 + 8, 256, 0, stream>>>(CNT, TMP, PART, CW, WEFFB);

    // K4: rowptr | fixHB | zero fillpos
    k4_kernel<<<NSCB + 188 + NZB, 256, 0, stream>>>(TMP, PART, ROWPTR, HB, CS, CNT + 1000);

    ush* KVr[4] = {KV0, KV1, KV2, KV3};
    const size_t nsr[4] = {(size_t)N_P, (size_t)N_D, (size_t)N_D, (size_t)N_P};
    const int foutf = (out_size != NT * 64 * 2) ? 1 : 0;

    for (int l = 0; l < 2; l++) {
        QKVArgs qk;
        qk.X = X;
        qk.Q = Q;
        for (int r = 0; r < 4; r++) {
            qk.KVk[r] = KVr[r];
            qk.KVv[r] = KVr[r] + nsr[r] * 64;
            qk.We[r] = WEFFB + (size_t)(l * 4 + r) * 8320;
        }
        for (int t = 0; t < 3; t++) {
            qk.Wq[t] = TW + TWQO + (size_t)(l * 3 + t) * 4096;
            qk.Bq[t] = CW + OFF_BQ + (l * 3 + t) * 64;
        }
        qkv_kernel<<<1658, 256, 17408, stream>>>(qk);

        if (l == 0) {
            FillArgs fa;
            fa.cb = cb;
            fa.HB = HB;
            fa.rowptr = ROWPTR;
            fa.fillpos = CNT;  // kernel indexes fillpos[1000+dst] -> CNT[1000..101000)
            fa.col = COL;
            fill_kernel<<<NHIST + NBLK_R1, 256, 20000, stream>>>(fa);
        }

        AggrArgs aa;
        aa.rowptr = ROWPTR;
        aa.col = COL;
        for (int r = 0; r < 4; r++) {
            aa.KVk[r] = KVr[r];
            aa.KVv[r] = KVr[r] + nsr[r] * 64;
        }
        aa.Q = Q;
        aa.prel = CW + OFF_PREL + l * 16;
        aa.OUT = OUT;
        aggr_kernel<<<5375, 256, 0, stream>>>(aa);

        EpiArgs ea;
        ea.O = OUT;
        ea.X = X;
        for (int t = 0; t < 3; t++) {
            ea.W[t] = TW + TWAO + (size_t)(l * 3 + t) * 4096;
            ea.Bb[t] = CW + OFF_BA + (l * 3 + t) * 64;
        }
        ea.skipv = CW + OFF_SKIP + l * 3;
        ea.fout = d_out;
        ea.foutf = foutf;
        ea.last = (l == 1) ? 1 : 0;
        epi_kernel<<<1658, 256, 0, stream>>>(ea);
    }
}

// Round 8
// 350.240 us; speedup vs baseline: 1.1021x; 1.0249x over previous
//
#include <hip/hip_runtime.h>
#include <cmath>

typedef unsigned short ush;  // bf16 raw bits
typedef __attribute__((ext_vector_type(8))) short short8;
typedef __attribute__((ext_vector_type(4))) float floatx4;

static constexpr int N_P = 100000, N_D = 1000, N_S = 5000, NT = N_P + N_D + N_S;
static constexpr int NC = 111000;  // concatenated dst slots: r0:1000 | r1:100000 | r2:5000 | r3:5000
static constexpr int E_TOT = 800000;

// hist-CSR geometry
static constexpr int NB0 = 128, NB2 = 64, NB3 = 64;
static constexpr int CH0 = (300000 + NB0 - 1) / NB0;  // 2344
static constexpr int CH2 = (100000 + NB2 - 1) / NB2;  // 1563
static constexpr int HB0_OFF = 0;
static constexpr int HB2_OFF = NB0 * 1000;            // 128000
static constexpr int HB3_OFF = HB2_OFF + NB2 * 5000;  // 448000 -> total 768000
static constexpr int NCH0 = NB0 / 16, NCH2 = NB2 / 16;  // 8, 4
static constexpr int CS0_OFF = 0;
static constexpr int CS2_OFF = NCH0 * 1000;            // 8000
static constexpr int CS3_OFF = CS2_OFF + NCH2 * 5000;  // 28000 -> total 48000
static constexpr int NHIST = NB0 + NB2 + NB3;          // 256
static constexpr int NBLK_R1 = (300000 + 255) / 256;   // 1172
static constexpr int NZB = (100000 + 255) / 256;       // 391

__device__ __forceinline__ float b2f(ush b) { return __uint_as_float(((unsigned)b) << 16); }
__device__ __forceinline__ ush f2b(float f) {
    unsigned u = __float_as_uint(f);
    return (ush)((u + 0x7FFFu + ((u >> 16) & 1u)) >> 16);
}

// canonical weight-block offsets (bf16 elements), d_in[3..20]
static constexpr size_t OFF_WINP = 0;
static constexpr size_t OFF_BINP = 4096;
static constexpr size_t OFF_WIND = 4160;
static constexpr size_t OFF_BIND = 12352;
static constexpr size_t OFF_WINS = 12416;
static constexpr size_t OFF_BINS = 16512;
static constexpr size_t OFF_WK = 16576;
static constexpr size_t OFF_BK = 41152;
static constexpr size_t OFF_WQ = 41536;
static constexpr size_t OFF_BQ = 66112;
static constexpr size_t OFF_WV = 66496;
static constexpr size_t OFF_BV = 91072;
static constexpr size_t OFF_WA = 91456;
static constexpr size_t OFF_BA = 116032;
static constexpr size_t OFF_AREL = 116416;
static constexpr size_t OFF_MREL = 124608;
static constexpr size_t OFF_PREL = 132800;
static constexpr size_t OFF_SKIP = 132832;
static constexpr size_t CW_TOTAL = 132838;
static constexpr int NCONVB = (int)((CW_TOTAL + 255) / 256);  // 519
static constexpr int NSCB = (NC + 1 + 255) / 256;             // 434

// fragment-layout weight buffer (ush elements)
static constexpr size_t TWINP = 0;      // 4096  (64x64)
static constexpr size_t TWIND = 4096;   // 8192  (128x64)
static constexpr size_t TWINS = 12288;  // 4096
static constexpr size_t TWQO = 16384;   // 6*4096 (l*3+t)
static constexpr size_t TWAO = 40960;   // 6*4096
static constexpr size_t TW_TOTAL = 65536;
static constexpr int NTWB = (int)(TW_TOTAL / 256);  // 256

struct ConvArgs {
    const void* src[18];
    long cum[19];
    int fl[18];  // 1 = fp32 source, 0 = bf16 source (host-derived from in_sizes)
};

struct CsrB {
    const int* ei[3];  // r0, r2, r3 edge arrays
    const int* ei1;    // r1
};

__device__ __forceinline__ void hist_geom(int b, const CsrB& c, int& r, const int*& ei, int& E,
                                          int& ndst, int& e0, int& e1, int& hb) {
    if (b < NB0) {
        r = 0; ei = c.ei[0]; E = 300000; ndst = 1000;
        e0 = b * CH0; hb = HB0_OFF + b * 1000;
    } else if (b < NB0 + NB2) {
        r = 1; ei = c.ei[1]; E = 100000; ndst = 5000;
        e0 = (b - NB0) * CH2; hb = HB2_OFF + (b - NB0) * 5000;
    } else {
        r = 2; ei = c.ei[2]; E = 100000; ndst = 5000;
        e0 = (b - NB0 - NB2) * CH2; hb = HB3_OFF + (b - NB0 - NB2) * 5000;
    }
    e1 = min(E, e0 + ((r == 0) ? CH0 : CH2));
}

__device__ __forceinline__ bool cs_geom(int g, int& idx0, int& step) {
    if (g >= 48000) return false;
    if (g < 8000) {
        int c = g / 1000, d = g % 1000;
        idx0 = HB0_OFF + c * 16 * 1000 + d; step = 1000;
    } else if (g < 28000) {
        int gg = g - 8000, c = gg / 5000, d = gg % 5000;
        idx0 = HB2_OFF + c * 16 * 5000 + d; step = 5000;
    } else {
        int gg = g - 28000, c = gg / 5000, d = gg % 5000;
        idx0 = HB3_OFF + c * 16 * 5000 + d; step = 5000;
    }
    return true;
}

// ---------------------------------------------------------------------------
// K1: convert weights | zero CNT r1 | histograms | fragment-transpose weights.
// Fragment layout for [K][64] weight: frag f = s*4+c holds, for lane l elem j:
//   W[(32s + ((l>>4)<<3) + j)*64 + 16c + (l&15)]   at  TW[f*512 + l*8 + j].
// ---------------------------------------------------------------------------
__global__ __launch_bounds__(256) void k1_kernel(ConvArgs a, ush* __restrict__ dst,
                                                 ush* __restrict__ tw,
                                                 int* __restrict__ cnt_r1, CsrB c,
                                                 int* __restrict__ HB) {
    const int b = blockIdx.x;
    if (b < NCONVB) {
        long g = (long)b * 256 + threadIdx.x;
        if (g >= (long)CW_TOTAL) return;
        int t = 0;
        while (g >= a.cum[t + 1]) t++;
        long i = g - a.cum[t];
        float v = a.fl[t] ? ((const float*)a.src[t])[i] : b2f(((const ush*)a.src[t])[i]);
        dst[g] = f2b(v);
    } else if (b < NCONVB + NZB) {
        int g = (b - NCONVB) * 256 + threadIdx.x;
        if (g < 100000) cnt_r1[g] = 0;
    } else if (b < NCONVB + NZB + NHIST) {
        __shared__ int h[5000];
        int r, E, ndst, e0, e1, hb;
        const int* ei;
        hist_geom(b - NCONVB - NZB, c, r, ei, E, ndst, e0, e1, hb);
        for (int d = threadIdx.x; d < ndst; d += 256) h[d] = 0;
        __syncthreads();
        for (int e = e0 + threadIdx.x; e < e1; e += 256) atomicAdd(&h[ei[E + e]], 1);
        __syncthreads();
        for (int d = threadIdx.x; d < ndst; d += 256) HB[hb + d] = h[d];
    } else {
        int g = (b - NCONVB - NZB - NHIST) * 256 + threadIdx.x;  // [0, 65536)
        const void* src; int fl; long ibase; int e;
        if (g < 4096) { src = a.src[0]; fl = a.fl[0]; e = g; ibase = 0; }
        else if (g < 12288) { src = a.src[2]; fl = a.fl[2]; e = g - 4096; ibase = 0; }
        else if (g < 16384) { src = a.src[4]; fl = a.fl[4]; e = g - 12288; ibase = 0; }
        else if (g < 40960) { int ee = g - 16384; src = a.src[8]; fl = a.fl[8];
                              e = ee & 4095; ibase = (long)(ee >> 12) * 4096; }
        else { int ee = g - 40960; src = a.src[12]; fl = a.fl[12];
               e = ee & 4095; ibase = (long)(ee >> 12) * 4096; }
        int f = e >> 9, l = (e >> 3) & 63, j = e & 7;
        int s = f >> 2, cc = f & 3;
        long in = ibase + (long)(32 * s + ((l >> 4) << 3) + j) * 64 + 16 * cc + (l & 15);
        float v = fl ? ((const float*)src)[in] : b2f(((const ush*)src)[in]);
        tw[g] = f2b(v);
    }
}

// ---------------------------------------------------------------------------
// MFMA building blocks: memcpy B-staging from fragment-layout weights,
// LDS-staged coalesced output stores.
// ---------------------------------------------------------------------------
template <int K>
__device__ __forceinline__ void stage_A(short* sA, const ush* __restrict__ X, int M, int row0) {
    for (int cid = threadIdx.x; cid < 64 * K / 8; cid += 256) {
        int r = cid / (K / 8), c0 = (cid % (K / 8)) * 8;
        int row = row0 + r;
        short8 v = {0, 0, 0, 0, 0, 0, 0, 0};
        if (row < M) v = *(const short8*)(const void*)(X + (size_t)row * K + c0);
        *(short8*)(&sA[r * (K + 8) + c0]) = v;
    }
}

template <int K>
__device__ __forceinline__ void stage_A_raw(short* sA, const void* __restrict__ X, int f,
                                            int M, int row0) {
    for (int cid = threadIdx.x; cid < 64 * K / 8; cid += 256) {
        int r = cid / (K / 8), c0 = (cid % (K / 8)) * 8;
        int row = row0 + r;
        short8 v = {0, 0, 0, 0, 0, 0, 0, 0};
        if (row < M) {
            if (f) {
                const floatx4* fp = (const floatx4*)((const float*)X + (size_t)row * K + c0);
                floatx4 f0 = fp[0], f1 = fp[1];
#pragma unroll
                for (int j = 0; j < 4; j++) v[j] = (short)f2b(f0[j]);
#pragma unroll
                for (int j = 0; j < 4; j++) v[4 + j] = (short)f2b(f1[j]);
            } else {
                v = *(const short8*)(const void*)((const ush*)X + (size_t)row * K + c0);
            }
        }
        *(short8*)(&sA[r * (K + 8) + c0]) = v;
    }
}

// W is fragment-layout. Output 64x64, staged through sB region (free after MFMA).
template <int K>
__device__ __forceinline__ void gemm_core64(const short* sA, short* sB,
                                            const ush* __restrict__ W, const ush* __restrict__ Bb,
                                            ush* __restrict__ Y, int M, int row0) {
    constexpr int NF = (K / 32) * 4;
    const int tid = threadIdx.x;
    for (int u = tid; u < NF * 64; u += 256)
        *(short8*)(&sB[u * 8]) = *(const short8*)(const void*)(W + (size_t)u * 8);
    __syncthreads();
    const int w = tid >> 6, l = tid & 63;
    floatx4 acc[4];
#pragma unroll
    for (int c = 0; c < 4; c++) {
        float bv = b2f(Bb[16 * c + (l & 15)]);
        acc[c] = (floatx4){bv, bv, bv, bv};
    }
#pragma unroll
    for (int s = 0; s < K / 32; s++) {
        short8 a = *(const short8*)(&sA[(16 * w + (l & 15)) * (K + 8) + 32 * s + ((l >> 4) << 3)]);
#pragma unroll
        for (int c = 0; c < 4; c++) {
            short8 b = *(const short8*)(&sB[(s * 4 + c) * 512 + l * 8]);
            acc[c] = __builtin_amdgcn_mfma_f32_16x16x32_bf16(a, b, acc[c], 0, 0, 0);
        }
    }
    __syncthreads();
#pragma unroll
    for (int c = 0; c < 4; c++)
#pragma unroll
        for (int r = 0; r < 4; r++)
            sB[(16 * w + ((l >> 4) << 2) + r) * 72 + 16 * c + (l & 15)] =
                (short)f2b(acc[c][r]);
    __syncthreads();
    for (int u = tid; u < 512; u += 256) {
        int r = u >> 3, c0 = (u & 7) * 8;
        int row = row0 + r;
        if (row < M)
            *(short8*)(Y + (size_t)row * 64 + c0) = *(const short8*)(&sB[r * 72 + c0]);
    }
}

// ---------------------------------------------------------------------------
// 5-panel streaming QKV gemm: A-fragments in registers (sA freed -> output
// stage), per panel {stage 8KB B, 8 MFMAs, scatter, coalesced store}.
// LDS: sA 9216 B + sB 8192 B = 17408 B -> 8+ blocks/CU (vs 3 at 50KB).
// Panels: 0=Q, 1=relA.K, 2=relA.V, 3=relB.K, 4=relB.V (all ld-64).
// ---------------------------------------------------------------------------
template <int NP>
__device__ __forceinline__ void gemm_panels(short* sA, short* sB,
                                            const ush* __restrict__ Wq,
                                            const ush* __restrict__ Bq, ush* __restrict__ Yq,
                                            const ush* __restrict__ WeA,
                                            ush* __restrict__ YAk, ush* __restrict__ YAv,
                                            const ush* __restrict__ WeB,
                                            ush* __restrict__ YBk, ush* __restrict__ YBv,
                                            int M, int row0) {
    const int tid = threadIdx.x;
    const int w = tid >> 6, l = tid & 63;
    __syncthreads();  // stage_A visible
    short8 a0 = *(const short8*)(&sA[(16 * w + (l & 15)) * 72 + ((l >> 4) << 3)]);
    short8 a1 = *(const short8*)(&sA[(16 * w + (l & 15)) * 72 + 32 + ((l >> 4) << 3)]);
    ush* dst[5] = {Yq, YAk, YAv, YBk, YBv};
#pragma unroll
    for (int p = 0; p < NP; p++) {
        __syncthreads();  // prev MFMA done with sB; prev store done with sA-out; a-regs loaded
        const ush* base = (p == 0) ? Wq : ((p <= 2) ? WeA : WeB);
        const int nw = (p == 0) ? 4 : 8;
        const int moff = (p == 0 || p == 1 || p == 3) ? 0 : 4;
        for (int u = tid; u < 512; u += 256) {
            int f = u >> 6, k = u & 63;  // f = s*4 + c
            int s = f >> 2, c = f & 3;
            const ush* src = base + (size_t)(s * nw + moff + c) * 512;
            *(short8*)(&sB[f * 512 + k * 8]) = *(const short8*)(const void*)(src + k * 8);
        }
        __syncthreads();
        const ush* bias = (p == 0) ? Bq : ((p <= 2) ? WeA + 8192 : WeB + 8192);
        const int boff = (p == 0 || p == 1 || p == 3) ? 0 : 64;
        floatx4 acc[4];
#pragma unroll
        for (int c = 0; c < 4; c++) {
            float bv = b2f(bias[boff + 16 * c + (l & 15)]);
            acc[c] = (floatx4){bv, bv, bv, bv};
        }
#pragma unroll
        for (int c = 0; c < 4; c++) {
            short8 b0 = *(const short8*)(&sB[c * 512 + l * 8]);
            acc[c] = __builtin_amdgcn_mfma_f32_16x16x32_bf16(a0, b0, acc[c], 0, 0, 0);
            short8 b1 = *(const short8*)(&sB[(4 + c) * 512 + l * 8]);
            acc[c] = __builtin_amdgcn_mfma_f32_16x16x32_bf16(a1, b1, acc[c], 0, 0, 0);
        }
        // scatter to sA-out (prev store reads finished before this panel's top barrier)
#pragma unroll
        for (int c = 0; c < 4; c++)
#pragma unroll
            for (int r = 0; r < 4; r++)
                sA[(16 * w + ((l >> 4) << 2) + r) * 72 + 16 * c + (l & 15)] =
                    (short)f2b(acc[c][r]);
        __syncthreads();
        ush* Y = dst[p];
        for (int u = tid; u < 512; u += 256) {
            int r = u >> 3, c0 = (u & 7) * 8;
            int row = row0 + r;
            if (row < M)
                *(short8*)(Y + (size_t)row * 64 + c0) = *(const short8*)(&sA[r * 72 + c0]);
        }
    }
}

// ---------------------------------------------------------------------------
// K2: fused input projections | chunk-scan | r1 counts. Dyn LDS: 33792 B.
// ---------------------------------------------------------------------------
struct K2Args {
    const void* raw[3];
    int f[3];
    const ush* W[3];   // fragment layout (TW)
    const ush* Bb[3];
    ush* X;
    const int* HB;
    int* CS;
    int* cnt;
    const int* ei1;
};

__global__ __launch_bounds__(256) void k2_kernel(K2Args a) {
    extern __shared__ short smem[];
    const int b = blockIdx.x;
    if (b < 1658) {
        if (b < 1563) {
            short* sA = smem; short* sB = smem + 64 * 72;
            stage_A_raw<64>(sA, a.raw[0], a.f[0], N_P, b * 64);
            gemm_core64<64>(sA, sB, a.W[0], a.Bb[0], a.X, N_P, b * 64);
        } else if (b < 1579) {
            short* sA = smem; short* sB = smem + 64 * 136;
            stage_A_raw<128>(sA, a.raw[1], a.f[1], N_D, (b - 1563) * 64);
            gemm_core64<128>(sA, sB, a.W[1], a.Bb[1], a.X + (size_t)N_P * 64, N_D,
                             (b - 1563) * 64);
        } else {
            short* sA = smem; short* sB = smem + 64 * 72;
            stage_A_raw<64>(sA, a.raw[2], a.f[2], N_S, (b - 1579) * 64);
            gemm_core64<64>(sA, sB, a.W[2], a.Bb[2], a.X + (size_t)(N_P + N_D) * 64, N_S,
                            (b - 1579) * 64);
        }
    } else if (b < 1701) {
        int d = (b - 1658) * 256 + threadIdx.x;
        if (d >= 11000) return;
        int ld_, nch, base, step, cs0, csstep, roff;
        if (d < 1000) { ld_ = d; nch = NCH0; base = HB0_OFF + ld_; step = 1000;
                        cs0 = CS0_OFF + ld_; csstep = 1000; roff = 0; }
        else if (d < 6000) { ld_ = d - 1000; nch = NCH2; base = HB2_OFF + ld_; step = 5000;
                             cs0 = CS2_OFF + ld_; csstep = 5000; roff = 101000; }
        else { ld_ = d - 6000; nch = NCH2; base = HB3_OFF + ld_; step = 5000;
               cs0 = CS3_OFF + ld_; csstep = 5000; roff = 106000; }
        int run = 0;
        for (int cc = 0; cc < nch; cc++) {
            int s = 0;
#pragma unroll
            for (int bb = 0; bb < 16; bb++) s += a.HB[base + (cc * 16 + bb) * step];
            a.CS[cs0 + cc * csstep] = run;
            run += s;
        }
        a.cnt[roff + ld_] = run;
    } else {
        int g = (b - 1701) * 256 + threadIdx.x;
        if (g < 300000) atomicAdd(&a.cnt[1000 + a.ei1[300000 + g]], 1);
    }
}

// ---------------------------------------------------------------------------
// K3: scanA | eff weight folding, emitted directly in fragment layout.
// ---------------------------------------------------------------------------
__global__ __launch_bounds__(256) void k3_kernel(const int* __restrict__ cnt,
                                                 int* __restrict__ tmp,
                                                 int* __restrict__ part,
                                                 const ush* __restrict__ CW,
                                                 ush* __restrict__ weff) {
    const int b = blockIdx.x;
    if (b < 109) {
        __shared__ int ls[256];
        const int t = threadIdx.x;
        const int base = b * 1024 + t * 4;
        int v[4];
#pragma unroll
        for (int j = 0; j < 4; j++) v[j] = (base + j < NC) ? cnt[base + j] : 0;
        int tsum = v[0] + v[1] + v[2] + v[3];
        ls[t] = tsum;
        __syncthreads();
        for (int off = 1; off < 256; off <<= 1) {
            int y = (t >= off) ? ls[t - off] : 0;
            __syncthreads();
            ls[t] += y;
            __syncthreads();
        }
        int run = ls[t] - tsum;
#pragma unroll
        for (int j = 0; j < 4; j++) {
            if (base + j < NC) tmp[base + j] = run;
            run += v[j];
        }
        if (t == 255) part[b] = ls[255];
    } else {
        const int eb = b - 109;  // l*4+r
        const int l = eb >> 2, r = eb & 3;
        const int st_of[4] = {0, 1, 1, 0};
        const int st = st_of[r];
        ush* out = weff + (size_t)eb * 8320;
        for (int idx = threadIdx.x; idx < 8320; idx += 256) {
            int k, n;
            if (idx < 8192) {
                int f = idx >> 9, ll = (idx >> 3) & 63, j = idx & 7;
                int s = f >> 3, c = f & 7;
                k = 32 * s + ((ll >> 4) << 3) + j;
                n = 16 * c + (ll & 15);
            } else { k = -1; n = idx - 8192; }
            int kv = n >= 64;
            int jj = n & 63, h = jj >> 4, e = jj & 15;
            const ush* W = CW + (kv ? OFF_WV : OFF_WK) + (size_t)(l * 3 + st) * 4096;
            const ush* B = CW + (kv ? OFF_BV : OFF_BK) + (size_t)(l * 3 + st) * 64;
            const ush* R = CW + (kv ? OFF_MREL : OFF_AREL) + (size_t)(l * 4 + r) * 1024;
            float acc = 0.f;
            if (k >= 0) {
#pragma unroll
                for (int d = 0; d < 16; d++)
                    acc += b2f(W[k * 64 + h * 16 + d]) * b2f(R[h * 256 + d * 16 + e]);
            } else {
#pragma unroll
                for (int d = 0; d < 16; d++)
                    acc += b2f(B[h * 16 + d]) * b2f(R[h * 256 + d * 16 + e]);
            }
            out[idx] = f2b(acc);
        }
    }
}

// ---------------------------------------------------------------------------
// K4: rowptr (inline partial rescan) | fixHB | zero fillpos.
// ---------------------------------------------------------------------------
__global__ __launch_bounds__(256) void k4_kernel(const int* __restrict__ tmp,
                                                 const int* __restrict__ part,
                                                 int* __restrict__ rowptr,
                                                 int* __restrict__ HB,
                                                 const int* __restrict__ CS,
                                                 int* __restrict__ fillpos) {
    const int b = blockIdx.x;
    if (b < NSCB) {
        __shared__ int ls[256];
        const int t = threadIdx.x;
        ls[t] = (t < 109) ? part[t] : 0;
        __syncthreads();
        for (int off = 1; off < 256; off <<= 1) {
            int y = (t >= off) ? ls[t - off] : 0;
            __syncthreads();
            ls[t] += y;
            __syncthreads();
        }
        int i = b * 256 + t;
        if (i <= NC)
            rowptr[i] = (i == NC) ? ls[255] : tmp[i] + ((i >> 10) ? ls[(i >> 10) - 1] : 0);
    } else if (b < NSCB + 188) {
        int g = (b - NSCB) * 256 + threadIdx.x;
        int idx0, step;
        if (!cs_geom(g, idx0, step)) return;
        int run = CS[g];
#pragma unroll
        for (int bb = 0; bb < 16; bb++) {
            int t2 = HB[idx0 + bb * step];
            HB[idx0 + bb * step] = run;
            run += t2;
        }
    } else {
        int g = (b - NSCB - 188) * 256 + threadIdx.x;
        if (g < 100000) fillpos[g] = 0;
    }
}

// ---------------------------------------------------------------------------
// qkv: wide Q+KV projections (1658 blocks). Dyn LDS: 17408 B.
// ---------------------------------------------------------------------------
struct QKVArgs {
    const ush* X;
    ush* Q;
    ush* KVk[4];
    ush* KVv[4];
    const ush* Wq[3];  // fragment layout (TW)
    const ush* Bq[3];
    const ush* We[4];  // fragment layout (weff)
};

__global__ __launch_bounds__(256) void qkv_kernel(QKVArgs a) {
    extern __shared__ short smem[];
    const int b = blockIdx.x;
    short* sA = smem;
    short* sB = smem + 64 * 72;
    if (b < 1563) {
        stage_A<64>(sA, a.X, N_P, b * 64);
        gemm_panels<5>(sA, sB, a.Wq[0], a.Bq[0], a.Q,
                       a.We[0], a.KVk[0], a.KVv[0],
                       a.We[3], a.KVk[3], a.KVv[3], N_P, b * 64);
    } else if (b < 1579) {
        int lb = b - 1563;
        stage_A<64>(sA, a.X + (size_t)N_P * 64, N_D, lb * 64);
        gemm_panels<5>(sA, sB, a.Wq[1], a.Bq[1], a.Q + (size_t)N_P * 64,
                       a.We[1], a.KVk[1], a.KVv[1],
                       a.We[2], a.KVk[2], a.KVv[2], N_D, lb * 64);
    } else {
        int lb = b - 1579;
        stage_A<64>(sA, a.X + (size_t)(N_P + N_D) * 64, N_S, lb * 64);
        gemm_panels<1>(sA, sB, a.Wq[2], a.Bq[2], a.Q + (size_t)(N_P + N_D) * 64,
                       nullptr, nullptr, nullptr, nullptr, nullptr, nullptr,
                       N_S, lb * 64);
    }
}

// ---------------------------------------------------------------------------
// fill: CSR column fill (layer 0 only). Dyn LDS: 20000 B.
// ---------------------------------------------------------------------------
struct FillArgs {
    CsrB cb;
    const int* HB;
    const int* rowptr;
    int* fillpos;  // == CNT base; kernel indexes fillpos[1000 + dst]
    int* col;
};

__global__ __launch_bounds__(256) void fill_kernel(FillArgs a) {
    extern __shared__ short smem[];
    const int b = blockIdx.x;
    if (b < NHIST) {
        int* h = (int*)smem;
        int r, E, ndst, e0, e1, hb;
        const int* ei;
        hist_geom(b, a.cb, r, ei, E, ndst, e0, e1, hb);
        const int roff = (r == 0) ? 0 : (r == 1) ? 101000 : 106000;
        for (int d = threadIdx.x; d < ndst; d += 256) h[d] = a.rowptr[roff + d] + a.HB[hb + d];
        __syncthreads();
        for (int e = e0 + threadIdx.x; e < e1; e += 256) {
            int d = ei[E + e];
            int slot = atomicAdd(&h[d], 1);
            a.col[slot] = ei[e];
        }
    } else {
        int g = (b - NHIST) * 256 + threadIdx.x;
        if (g < 300000) {
            int gi = 1000 + a.cb.ei1[300000 + g];
            int slot = a.rowptr[gi] + atomicAdd(&a.fillpos[gi], 1);
            a.col[slot] = a.cb.ei1[g];
        }
    }
}

// ---------------------------------------------------------------------------
// Fused gather aggregation; K/V in split half-arrays; writes gelu(out) bf16.
// Fixed per-lane shift softmax (peeled first edge) -> independent iterations;
// unroll-2 software pipeline doubles outstanding gathers per lane (MLP).
// ---------------------------------------------------------------------------
struct AggrArgs {
    const int* rowptr;
    const int* col;
    const ush* KVk[4];
    const ush* KVv[4];
    const ush* Q;
    const ush* prel;
    ush* OUT;
};

template <int LANES>
__device__ __forceinline__ void seg_attn(const AggrArgs& a, int rel, int g, int h, int lane,
                                         const float* qf, float* o) {
    const int s0 = a.rowptr[g], s1 = a.rowptr[g + 1];
    const ush* Kb = a.KVk[rel];
    const ush* Vb = a.KVv[rel];
    const float ps = b2f(a.prel[rel * 4 + h]) * 0.25f;
    float m = -1e30f, s = 0.f;
    float acc[16];
#pragma unroll
    for (int i = 0; i < 16; i++) acc[i] = 0.f;
    int j = s0 + lane;
    if (j < s1) {
        // peeled first edge: defines the shift; exp(0) = 1
        {
            int src = a.col[j];
            const ush* kp = Kb + (size_t)src * 64 + h * 16;
            const ush* vp = Vb + (size_t)src * 64 + h * 16;
            short8 k0 = *(const short8*)(const void*)kp;
            short8 k1 = *(const short8*)(const void*)(kp + 8);
            short8 v0 = *(const short8*)(const void*)vp;
            short8 v1 = *(const short8*)(const void*)(vp + 8);
            float dot = 0.f;
#pragma unroll
            for (int i = 0; i < 8; i++) dot += qf[i] * b2f((ush)k0[i]);
#pragma unroll
            for (int i = 0; i < 8; i++) dot += qf[8 + i] * b2f((ush)k1[i]);
            m = dot * ps;
            s = 1.f;
#pragma unroll
            for (int i = 0; i < 8; i++) acc[i] = b2f((ush)v0[i]);
#pragma unroll
            for (int i = 0; i < 8; i++) acc[8 + i] = b2f((ush)v1[i]);
        }
        j += LANES;
        // unroll-2: both iterations' col+KV loads issue before either compute
        for (; j + LANES < s1; j += 2 * LANES) {
            int srcA = a.col[j];
            int srcB = a.col[j + LANES];
            const ush* kpA = Kb + (size_t)srcA * 64 + h * 16;
            const ush* vpA = Vb + (size_t)srcA * 64 + h * 16;
            const ush* kpB = Kb + (size_t)srcB * 64 + h * 16;
            const ush* vpB = Vb + (size_t)srcB * 64 + h * 16;
            short8 k0A = *(const short8*)(const void*)kpA;
            short8 k1A = *(const short8*)(const void*)(kpA + 8);
            short8 v0A = *(const short8*)(const void*)vpA;
            short8 v1A = *(const short8*)(const void*)(vpA + 8);
            short8 k0B = *(const short8*)(const void*)kpB;
            short8 k1B = *(const short8*)(const void*)(kpB + 8);
            short8 v0B = *(const short8*)(const void*)vpB;
            short8 v1B = *(const short8*)(const void*)(vpB + 8);
            float dotA = 0.f, dotB = 0.f;
#pragma unroll
            for (int i = 0; i < 8; i++) dotA += qf[i] * b2f((ush)k0A[i]);
#pragma unroll
            for (int i = 0; i < 8; i++) dotA += qf[8 + i] * b2f((ush)k1A[i]);
#pragma unroll
            for (int i = 0; i < 8; i++) dotB += qf[i] * b2f((ush)k0B[i]);
#pragma unroll
            for (int i = 0; i < 8; i++) dotB += qf[8 + i] * b2f((ush)k1B[i]);
            float eA = __expf(dotA * ps - m);
            float eB = __expf(dotB * ps - m);
            s += eA + eB;
#pragma unroll
            for (int i = 0; i < 8; i++) acc[i] += eA * b2f((ush)v0A[i]) + eB * b2f((ush)v0B[i]);
#pragma unroll
            for (int i = 0; i < 8; i++)
                acc[8 + i] += eA * b2f((ush)v1A[i]) + eB * b2f((ush)v1B[i]);
        }
        if (j < s1) {  // at most one tail edge
            int src = a.col[j];
            const ush* kp = Kb + (size_t)src * 64 + h * 16;
            const ush* vp = Vb + (size_t)src * 64 + h * 16;
            short8 k0 = *(const short8*)(const void*)kp;
            short8 k1 = *(const short8*)(const void*)(kp + 8);
            short8 v0 = *(const short8*)(const void*)vp;
            short8 v1 = *(const short8*)(const void*)(vp + 8);
            float dot = 0.f;
#pragma unroll
            for (int i = 0; i < 8; i++) dot += qf[i] * b2f((ush)k0[i]);
#pragma unroll
            for (int i = 0; i < 8; i++) dot += qf[8 + i] * b2f((ush)k1[i]);
            float e1 = __expf(dot * ps - m);
            s += e1;
#pragma unroll
            for (int i = 0; i < 8; i++) acc[i] += e1 * b2f((ush)v0[i]);
#pragma unroll
            for (int i = 0; i < 8; i++) acc[8 + i] += e1 * b2f((ush)v1[i]);
        }
    }
#pragma unroll
    for (int wd = LANES >> 1; wd >= 1; wd >>= 1) {
        float mo = __shfl_xor(m, wd);
        float so = __shfl_xor(s, wd);
        float nm = fmaxf(m, mo);
        float e0 = __expf(m - nm), e1 = __expf(mo - nm);
        s = s * e0 + so * e1;
#pragma unroll
        for (int i = 0; i < 16; i++) {
            float ao = __shfl_xor(acc[i], wd);
            acc[i] = acc[i] * e0 + ao * e1;
        }
        m = nm;
    }
    float inv = 1.f / (s + 1e-16f);
#pragma unroll
    for (int i = 0; i < 16; i++) o[i] += acc[i] * inv;
}

template <int LANES>
__device__ __forceinline__ void job_run(const AggrArgs& a, int wid, int nd, int rel, int roff,
                                        size_t xoff, int rel2, int roff2) {
    const int lane = wid % LANES;
    const int grp = wid / LANES;
    const int d = grp >> 2, h = grp & 3;
    if (d >= nd) return;
    const ush* qp = a.Q + xoff + (size_t)d * 64 + h * 16;
    short8 q0 = *(const short8*)(const void*)qp;
    short8 q1 = *(const short8*)(const void*)(qp + 8);
    float qf[16];
#pragma unroll
    for (int i = 0; i < 8; i++) { qf[i] = b2f((ush)q0[i]); qf[8 + i] = b2f((ush)q1[i]); }
    float o[16];
#pragma unroll
    for (int i = 0; i < 16; i++) o[i] = 0.f;
    seg_attn<LANES>(a, rel, roff + d, h, lane, qf, o);
    if (rel2 >= 0) seg_attn<LANES>(a, rel2, roff2 + d, h, lane, qf, o);
    if (lane == 0) {
        ush* op = a.OUT + xoff + (size_t)d * 64 + h * 16;
        short8 w0, w1;
#pragma unroll
        for (int i = 0; i < 8; i++) {
            float va = o[i];
            w0[i] = (short)f2b(0.5f * va * (1.0f + erff(va * 0.70710678118654752f)));
            float vb = o[8 + i];
            w1[i] = (short)f2b(0.5f * vb * (1.0f + erff(vb * 0.70710678118654752f)));
        }
        *(short8*)(op) = w0;
        *(short8*)(op + 8) = w1;
    }
}

// blocks: [0,250) drugs L=16 | [250,563) diseases L=4 | [563,3688) patients L=2
__global__ __launch_bounds__(256) void aggr_kernel(AggrArgs a) {
    const int b = blockIdx.x, t = threadIdx.x;
    if (b < 250) {
        job_run<16>(a, b * 256 + t, N_D, 0, 0, (size_t)N_P * 64, -1, 0);
    } else if (b < 563) {
        job_run<4>(a, (b - 250) * 256 + t, N_S, 2, 101000, (size_t)(N_P + N_D) * 64, 3, 106000);
    } else {
        job_run<2>(a, (b - 563) * 256 + t, N_P, 1, 1000, 0, -1, 0);
    }
}

// ---------------------------------------------------------------------------
// Batched MFMA epilogue: x = s*(OUT @ Wa + ba) + (1-s)*x.  B via fragment
// memcpy staging; blend+store via fp32 LDS chunks (coalesced X read & write).
// ---------------------------------------------------------------------------
struct EpiArgs {
    const ush* O;
    ush* X;
    const ush* W[3];  // fragment layout (TWA)
    const ush* Bb[3];
    const ush* skipv;
    void* fout;
    int foutf;  // 1 = final output fp32, 0 = bf16
    int last;
};

__global__ __launch_bounds__(256) void epi_kernel(EpiArgs a) {
    const int b = blockIdx.x;
    int t, lb, M;
    size_t noff;
    if (b < 1563) { t = 0; lb = b; M = N_P; noff = 0; }
    else if (b < 1579) { t = 1; lb = b - 1563; M = N_D; noff = (size_t)N_P; }
    else { t = 2; lb = b - 1579; M = N_S; noff = (size_t)(N_P + N_D); }
    const ush* O = a.O + noff * 64;
    ush* X = a.X + noff * 64;
    const ush* WF = a.W[t];
    __shared__ short sA[64 * 72];  // 9216 B; reused as fp32 stage (32 x 68 floats)
    __shared__ short sB[8 * 512];
    const int tid = threadIdx.x;
    const int row0 = lb * 64;
    for (int cid = tid; cid < 512; cid += 256) {
        int r = cid >> 3, c0 = (cid & 7) * 8;
        int row = row0 + r;
        short8 sv = {0, 0, 0, 0, 0, 0, 0, 0};
        if (row < M) sv = *(const short8*)(const void*)(O + (size_t)row * 64 + c0);
        *(short8*)(&sA[r * 72 + c0]) = sv;
    }
    for (int u = tid; u < 512; u += 256)
        *(short8*)(&sB[u * 8]) = *(const short8*)(const void*)(WF + (size_t)u * 8);
    __syncthreads();
    const float sg = 1.f / (1.f + expf(-b2f(a.skipv[t])));
    const int w = tid >> 6, l = tid & 63;
    floatx4 acc[4];
#pragma unroll
    for (int c = 0; c < 4; c++) {
        float bv = b2f(a.Bb[t][16 * c + (l & 15)]);
        acc[c] = (floatx4){bv, bv, bv, bv};
    }
#pragma unroll
    for (int s = 0; s < 2; s++) {
        short8 av = *(const short8*)(&sA[(16 * w + (l & 15)) * 72 + 32 * s + ((l >> 4) << 3)]);
#pragma unroll
        for (int c = 0; c < 4; c++) {
            short8 bv = *(const short8*)(&sB[(s * 4 + c) * 512 + l * 8]);
            acc[c] = __builtin_amdgcn_mfma_f32_16x16x32_bf16(av, bv, acc[c], 0, 0, 0);
        }
    }
    float* sOf = (float*)sA;
#pragma unroll
    for (int ch = 0; ch < 2; ch++) {
        __syncthreads();
        if ((w >> 1) == ch) {
#pragma unroll
            for (int c = 0; c < 4; c++)
#pragma unroll
                for (int r = 0; r < 4; r++)
                    sOf[(16 * (w & 1) + ((l >> 4) << 2) + r) * 68 + 16 * c + (l & 15)] =
                        acc[c][r];
        }
        __syncthreads();
        {
            int r = tid >> 3, c0 = (tid & 7) * 8;
            int row = row0 + ch * 32 + r;
            if (row < M) {
                floatx4 f0 = *(const floatx4*)(&sOf[r * 68 + c0]);
                floatx4 f1 = *(const floatx4*)(&sOf[r * 68 + c0 + 4]);
                short8 xv = *(const short8*)(const void*)(X + (size_t)row * 64 + c0);
                float vo[8];
#pragma unroll
                for (int j = 0; j < 4; j++) vo[j] = sg * f0[j] + (1.f - sg) * b2f((ush)xv[j]);
#pragma unroll
                for (int j = 0; j < 4; j++)
                    vo[4 + j] = sg * f1[j] + (1.f - sg) * b2f((ush)xv[4 + j]);
                if (!a.last) {
                    short8 ov;
#pragma unroll
                    for (int j = 0; j < 8; j++) ov[j] = (short)f2b(vo[j]);
                    *(short8*)(X + (size_t)row * 64 + c0) = ov;
                } else {
                    size_t goff = (noff + row) * 64 + c0;
                    if (a.foutf) {
                        floatx4 o0, o1;
#pragma unroll
                        for (int j = 0; j < 4; j++) { o0[j] = vo[j]; o1[j] = vo[4 + j]; }
                        *(floatx4*)((float*)a.fout + goff) = o0;
                        *(floatx4*)((float*)a.fout + goff + 4) = o1;
                    } else {
                        short8 ov;
#pragma unroll
                        for (int j = 0; j < 8; j++) ov[j] = (short)f2b(vo[j]);
                        *(short8*)((ush*)a.fout + goff) = ov;
                    }
                }
            }
        }
    }
}

// ---------------------------------------------------------------------------
extern "C" void kernel_launch(void* const* d_in, const int* in_sizes, int n_in,
                              void* d_out, int out_size, void* d_ws, size_t ws_size,
                              hipStream_t stream) {
    // ---- Workspace layout ----
    char* w = (char*)d_ws;
    w += 64;
    ush* CW = (ush*)w;      w += ((CW_TOTAL * 2 + 63) / 64) * 64;
    ush* WEFFB = (ush*)w;   w += ((size_t)8 * 8320 * 2 + 63) / 64 * 64;
    ush* TW = (ush*)w;      w += (size_t)TW_TOTAL * 2;
    ush* X = (ush*)w;       w += (size_t)NT * 64 * 2;
    ush* Q = (ush*)w;       w += (size_t)NT * 64 * 2;
    ush* KV0 = (ush*)w;     w += (size_t)N_P * 128 * 2;
    ush* KV1 = (ush*)w;     w += (size_t)N_D * 128 * 2;
    ush* KV2 = (ush*)w;     w += (size_t)N_D * 128 * 2;
    ush* KV3 = (ush*)w;     w += (size_t)N_P * 128 * 2;
    ush* OUT = (ush*)w;     w += (size_t)NT * 64 * 4;  // fp32-size slab: HB/CS overlay below
    int* CNT = (int*)w;     w += (size_t)NC * 4;  // r1 region doubles as fillpos
    int* TMP = (int*)w;     w += (size_t)NC * 4;
    int* PART = (int*)w;    w += 512;
    int* ROWPTR = (int*)w;  w += (size_t)(NC + 1) * 4;
    int* COL = (int*)w;     w += (size_t)E_TOT * 4;
    int* HB = (int*)OUT;           // 768000 ints, dead before aggr
    int* CS = (int*)OUT + 800000;  // 48000 ints, same overlay

    // dtype flags from byte sizes (bytes == 2*elems -> bf16, else fp32)
    static const long sz[18] = {4096, 64, 8192, 64, 4096, 64, 24576, 384, 24576, 384,
                                24576, 384, 24576, 384, 8192, 8192, 32, 6};
    ConvArgs ca;
    long cum = 0;
    for (int t = 0; t < 18; t++) {
        ca.src[t] = d_in[3 + t];
        ca.cum[t] = cum;
        ca.fl[t] = (in_sizes[3 + t] != (int)(sz[t] * 2)) ? 1 : 0;
        cum += sz[t];
    }
    ca.cum[18] = cum;

    CsrB cb;
    cb.ei[0] = (const int*)d_in[21];
    cb.ei[1] = (const int*)d_in[23];
    cb.ei[2] = (const int*)d_in[24];
    cb.ei1 = (const int*)d_in[22];

    // K1: convert weights | zero CNT r1 | histograms | fragment transposes
    k1_kernel<<<NCONVB + NZB + NHIST + NTWB, 256, 0, stream>>>(ca, CW, TW, CNT + 1000, cb, HB);

    // K2: input projections | chunk-scan | r1 degree counts
    K2Args k2;
    k2.raw[0] = d_in[0]; k2.f[0] = (in_sizes[0] != N_P * 64 * 2) ? 1 : 0;
    k2.raw[1] = d_in[1]; k2.f[1] = (in_sizes[1] != N_D * 128 * 2) ? 1 : 0;
    k2.raw[2] = d_in[2]; k2.f[2] = (in_sizes[2] != N_S * 64 * 2) ? 1 : 0;
    k2.W[0] = TW + TWINP; k2.Bb[0] = CW + OFF_BINP;
    k2.W[1] = TW + TWIND; k2.Bb[1] = CW + OFF_BIND;
    k2.W[2] = TW + TWINS; k2.Bb[2] = CW + OFF_BINS;
    k2.X = X;
    k2.HB = HB; k2.CS = CS; k2.cnt = CNT; k2.ei1 = cb.ei1;
    k2_kernel<<<1701 + NBLK_R1, 256, 33792, stream>>>(k2);

    // K3: scanA | eff folding (fragment layout)
    k3_kernel<<<109 + 8, 256, 0, stream>>>(CNT, TMP, PART, CW, WEFFB);

    // K4: rowptr | fixHB | zero fillpos
    k4_kernel<<<NSCB + 188 + NZB, 256, 0, stream>>>(TMP, PART, ROWPTR, HB, CS, CNT + 1000);

    ush* KVr[4] = {KV0, KV1, KV2, KV3};
    const size_t nsr[4] = {(size_t)N_P, (size_t)N_D, (size_t)N_D, (size_t)N_P};
    const int foutf = (out_size != NT * 64 * 2) ? 1 : 0;

    for (int l = 0; l < 2; l++) {
        QKVArgs qk;
        qk.X = X;
        qk.Q = Q;
        for (int r = 0; r < 4; r++) {
            qk.KVk[r] = KVr[r];
            qk.KVv[r] = KVr[r] + nsr[r] * 64;
            qk.We[r] = WEFFB + (size_t)(l * 4 + r) * 8320;
        }
        for (int t = 0; t < 3; t++) {
            qk.Wq[t] = TW + TWQO + (size_t)(l * 3 + t) * 4096;
            qk.Bq[t] = CW + OFF_BQ + (l * 3 + t) * 64;
        }
        qkv_kernel<<<1658, 256, 17408, stream>>>(qk);

        if (l == 0) {
            FillArgs fa;
            fa.cb = cb;
            fa.HB = HB;
            fa.rowptr = ROWPTR;
            fa.fillpos = CNT;  // kernel indexes fillpos[1000+dst] -> CNT[1000..101000)
            fa.col = COL;
            fill_kernel<<<NHIST + NBLK_R1, 256, 20000, stream>>>(fa);
        }

        AggrArgs aa;
        aa.rowptr = ROWPTR;
        aa.col = COL;
        for (int r = 0; r < 4; r++) {
            aa.KVk[r] = KVr[r];
            aa.KVv[r] = KVr[r] + nsr[r] * 64;
        }
        aa.Q = Q;
        aa.prel = CW + OFF_PREL + l * 16;
        aa.OUT = OUT;
        aggr_kernel<<<3688, 256, 0, stream>>>(aa);

        EpiArgs ea;
        ea.O = OUT;
        ea.X = X;
        for (int t = 0; t < 3; t++) {
            ea.W[t] = TW + TWAO + (size_t)(l * 3 + t) * 4096;
            ea.Bb[t] = CW + OFF_BA + (l * 3 + t) * 64;
        }
        ea.skipv = CW + OFF_SKIP + l * 3;
        ea.fout = d_out;
        ea.foutf = foutf;
        ea.last = (l == 1) ? 1 : 0;
        epi_kernel<<<1658, 256, 0, stream>>>(ea);
    }
}